// Round 6
// baseline (715.982 us; speedup 1.0000x reference)
//
#include <hip/hip_runtime.h>
#include <hip/hip_bf16.h>
#include <math.h>

// B=128, T=512, D=512, K=64; mid=64; rows per half = 32768
// Inputs f32. Output f32 (reference output dtype is float32).
typedef __attribute__((ext_vector_type(4))) float f32x4;

// ---------------- output offsets (f32 elements) ----------------
#define O_FM    0ULL
#define O_TRIP  67108864ULL
#define O_KL    67108865ULL
#define O_DIST  67108866ULL
#define O_AATT  67108867ULL
#define O_NATT  67141635ULL
#define O_ANATT 67174403ULL
#define O_NAATT 67207171ULL

// ---------------- ws offsets (bytes), total ~35 MB ----------------
#define WS_ATT   0ULL          // att f32 [65536][128] (k<64: vs Amem, k>=64: vs Nmem)
#define WS_PAM   33554432ULL   // P_A_mu  f32 [64][512]  (Amem @ W_mu)
#define WS_PNM   33685504ULL   // P_N_mu  f32 [64][512]  (Nmem @ W_mu)
#define WS_PNV   33816576ULL   // P_N_var f32 [64][512]  (Nmem @ W_var)
#define WS_MEMT  33947648ULL   // memT f32 [512][128] (memT[d][k], k<64:Amem else Nmem)
#define WS_TATT  34209792ULL   // t_att f32 [3][32768] (0=A_att,1=N_att,2=N_Aatt)
#define WS_IDX   34603008ULL   // int [3][64][40] (0=A_idx,1=N_idx,2=P_idx; 33 used)
#define WS_GATH  34633728ULL   // f32 [3][64][512]
#define WS_NORM  35026944ULL   // f32 [128]
#define WS_KL    35027456ULL   // f32 accumulator

__device__ __forceinline__ float blk_sum(float v, float* red) {
    #pragma unroll
    for (int o = 32; o; o >>= 1) v += __shfl_xor(v, o);
    int tid = threadIdx.x;
    if ((tid & 63) == 0) red[tid >> 6] = v;
    __syncthreads();
    float r = red[0] + red[1] + red[2] + red[3];
    __syncthreads();
    return r;
}

// ---------------- prep: memT transpose + kl zero ----------------
__global__ __launch_bounds__(256) void k_prep(const float* __restrict__ Amem, const float* __restrict__ Nmem,
                                              char* __restrict__ ws) {
    int i = blockIdx.x * 256 + threadIdx.x;
    if (i == 0) *(float*)(ws + WS_KL) = 0.f;
    int d = i >> 7, k = i & 127;
    float v = (k < 64) ? Amem[(size_t)k * 512 + d] : Nmem[(size_t)(k - 64) * 512 + d];
    ((float*)(ws + WS_MEMT))[i] = v;
}

// ---------------- proj: P = mem @ W, f32, stored [k][n] ----------------
__global__ __launch_bounds__(256) void k_proj(const float* __restrict__ Amem, const float* __restrict__ Nmem,
                                              const float* __restrict__ Wmu, const float* __restrict__ Wvar,
                                              float* __restrict__ pam, float* __restrict__ pnm,
                                              float* __restrict__ pnv) {
    __shared__ float mr[512];
    int mat = blockIdx.x >> 6, k = blockIdx.x & 63, tid = threadIdx.x;
    const float* mrow = ((mat == 0) ? Amem : Nmem) + (size_t)k * 512;
    const float* W = (mat == 2) ? Wvar : Wmu;
    mr[tid] = mrow[tid]; mr[tid + 256] = mrow[tid + 256];
    __syncthreads();
    float s0 = 0.f, s1 = 0.f;
    for (int d = 0; d < 512; ++d) {
        float m = mr[d];
        s0 += m * W[(size_t)d * 512 + tid];
        s1 += m * W[(size_t)d * 512 + tid + 256];
    }
    float* dst = (mat == 0) ? pam : ((mat == 1) ? pnm : pnv);
    dst[(size_t)k * 512 + tid] = s0;
    dst[(size_t)k * 512 + tid + 256] = s1;
}

// ---------------- dots: att f32, sigmoid, t_att top5, x->F_M left (f32 copy) ----------------
__global__ __launch_bounds__(256) void k_dots(const float* __restrict__ x, char* __restrict__ ws,
                                              float* __restrict__ out) {
    __shared__ float xs[64][66];
    __shared__ char smem[64 * 128 * 4];
    float (*ms)[128]   = (float(*)[128])smem;
    float (*attl)[128] = (float(*)[128])smem;

    int tid = threadIdx.x;
    int row0 = blockIdx.x * 64;
    const float* memT = (const float*)(ws + WS_MEMT);
    float* attw = (float*)(ws + WS_ATT);
    int ty = tid >> 4, tx = tid & 15;

    float acc[4][8];
    #pragma unroll
    for (int r = 0; r < 4; ++r)
        #pragma unroll
        for (int j = 0; j < 8; ++j) acc[r][j] = 0.f;

    for (int dc = 0; dc < 8; ++dc) {
        int d0 = dc * 64;
        {   // stage x tile + exact f32 copy into F_M left half
            int rr = tid >> 2, q = tid & 3;
            const float* src = x + (size_t)(row0 + rr) * 512 + d0 + q * 16;
            float* dst = out + (size_t)(row0 + rr) * 1024 + d0 + q * 16;
            #pragma unroll
            for (int j = 0; j < 4; ++j) {
                f32x4 v = *(const f32x4*)(src + j * 4);
                *(f32x4*)(dst + j * 4) = v;
                xs[rr][q * 16 + j * 4 + 0] = v.x; xs[rr][q * 16 + j * 4 + 1] = v.y;
                xs[rr][q * 16 + j * 4 + 2] = v.z; xs[rr][q * 16 + j * 4 + 3] = v.w;
            }
        }
        {   // stage memT chunk [64][128]
            const f32x4* src = (const f32x4*)(memT + (size_t)d0 * 128);
            f32x4* dstv = (f32x4*)&ms[0][0];
            #pragma unroll
            for (int j = 0; j < 8; ++j) dstv[tid + j * 256] = src[tid + j * 256];
        }
        __syncthreads();
        #pragma unroll 2
        for (int d = 0; d < 64; ++d) {
            f32x4 mlo = *(const f32x4*)&ms[d][tx * 8];
            f32x4 mhi = *(const f32x4*)&ms[d][tx * 8 + 4];
            #pragma unroll
            for (int r = 0; r < 4; ++r) {
                float xv = xs[ty * 4 + r][d];
                acc[r][0] += xv * mlo.x; acc[r][1] += xv * mlo.y;
                acc[r][2] += xv * mlo.z; acc[r][3] += xv * mlo.w;
                acc[r][4] += xv * mhi.x; acc[r][5] += xv * mhi.y;
                acc[r][6] += xv * mhi.z; acc[r][7] += xv * mhi.w;
            }
        }
        __syncthreads();
    }

    // sigmoid -> att f32 (ws + LDS for t_att)
    #pragma unroll
    for (int r = 0; r < 4; ++r) {
        float* dp = attw + (size_t)(row0 + ty * 4 + r) * 128 + tx * 8;
        #pragma unroll
        for (int j = 0; j < 8; ++j) {
            float logit = acc[r][j] * 0.044194173824159216f;  // 1/sqrt(512)
            float av = 1.f / (1.f + expf(-logit));
            attl[ty * 4 + r][tx * 8 + j] = av;
            dp[j] = av;
        }
    }
    __syncthreads();

    // t_att: top-5-of-64 via reduce-max + ballot knockout
    int lane = tid & 63, w = tid >> 6;
    float* tatt = (float*)(ws + WS_TATT);
    int half = row0 >> 15;
    for (int rr = 0; rr < 16; ++rr) {
        int r = w * 16 + rr;
        int lr = (row0 + r) & 32767;
        #pragma unroll
        for (int side = 0; side < 2; ++side) {
            float cur = attl[r][side * 64 + lane];
            float sum5 = 0.f;
            #pragma unroll
            for (int it = 0; it < 5; ++it) {
                float m = cur;
                #pragma unroll
                for (int o = 32; o; o >>= 1) { float t = __shfl_xor(m, o); m = fmaxf(m, t); }
                sum5 += m;
                unsigned long long bl = __ballot(cur == m);
                int srcl = __ffsll(bl) - 1;
                if (lane == srcl) cur = -INFINITY;
            }
            if (lane == 0) {
                float tv = sum5 / 5.f;
                if (half) {
                    if (side == 0) { out[O_AATT + lr]  = tv; tatt[lr] = tv; }
                    else           { out[O_NAATT + lr] = tv; tatt[2 * 32768 + lr] = tv; }
                } else {
                    if (side == 0) { out[O_ANATT + lr] = tv; }
                    else           { out[O_NATT + lr]  = tv; tatt[32768 + lr] = tv; }
                }
            }
        }
    }
}

// ---------------- top-33 over t for 3 matrices ----------------
__global__ __launch_bounds__(256) void k_topk(const float* __restrict__ tatt, int* __restrict__ idx) {
    __shared__ float vals[512];
    __shared__ float rv[256];
    __shared__ int   ri[256];
    int s = blockIdx.x >> 6;
    int b = blockIdx.x & 63;
    int tid = threadIdx.x;
    const float* src = tatt + (size_t)s * 32768 + b * 512;
    vals[tid] = src[tid]; vals[tid + 256] = src[tid + 256];
    __syncthreads();
    for (int it = 0; it < 33; ++it) {
        float a = vals[tid]; int ia = tid;
        float c = vals[tid + 256];
        if (c > a) { a = c; ia = tid + 256; }
        rv[tid] = a; ri[tid] = ia;
        __syncthreads();
        for (int st = 128; st > 0; st >>= 1) {
            if (tid < st) {
                float o = rv[tid + st]; int oi = ri[tid + st];
                if (o > rv[tid] || (o == rv[tid] && oi < ri[tid])) { rv[tid] = o; ri[tid] = oi; }
            }
            __syncthreads();
        }
        if (tid == 0) { idx[(s * 64 + b) * 40 + it] = ri[0]; vals[ri[0]] = -INFINITY; }
        __syncthreads();
    }
}

// ---------------- gather means of x over the 3 index sets ----------------
__global__ __launch_bounds__(256) void k_gather3(const float* __restrict__ x, const int* __restrict__ idx,
                                                 float* __restrict__ gath) {
    int b = blockIdx.x, tid = threadIdx.x;
    int d0 = tid * 2;
    #pragma unroll
    for (int s = 0; s < 3; ++s) {
        int srcb = (s == 1) ? b : 64 + b;
        const float* xb = x + (size_t)srcb * 512 * 512;
        float a0 = 0.f, a1 = 0.f;
        for (int i = 0; i < 33; ++i) {
            int t = idx[(s * 64 + b) * 40 + i];
            const float* p = xb + (size_t)t * 512 + d0;
            a0 += p[0]; a1 += p[1];
        }
        gath[((size_t)s * 64 + b) * 512 + d0]     = a0 / 33.f;
        gath[((size_t)s * 64 + b) * 512 + d0 + 1] = a1 / 33.f;
    }
}

// ---------------- triplet ----------------
__global__ __launch_bounds__(256) void k_triplet(const float* __restrict__ gath, float* __restrict__ out) {
    __shared__ float red[8];
    int tid = threadIdx.x;
    float trip = 0.f;
    for (int b = 0; b < 64; ++b) {
        const float* a = gath + (size_t)(64 + b) * 512;   // anchor
        const float* p = gath + (size_t)(128 + b) * 512;  // positive
        const float* n = gath + (size_t)(b) * 512;        // negative
        float a0 = a[tid], a1 = a[tid + 256];
        float p0 = p[tid], p1 = p[tid + 256];
        float n0 = n[tid], n1 = n[tid + 256];
        float na  = sqrtf(blk_sum(a0 * a0 + a1 * a1, red));
        float npv = sqrtf(blk_sum(p0 * p0 + p1 * p1, red));
        float nn  = sqrtf(blk_sum(n0 * n0 + n1 * n1, red));
        float e0 = a0 / na - p0 / npv + 1e-6f, e1 = a1 / na - p1 / npv + 1e-6f;
        float f0 = a0 / na - n0 / nn  + 1e-6f, f1 = a1 / na - n1 / nn  + 1e-6f;
        float dap = sqrtf(blk_sum(e0 * e0 + e1 * e1, red));
        float dan = sqrtf(blk_sum(f0 * f0 + f1 * f1, red));
        if (tid == 0) trip += fmaxf(dap - dan + 1.f, 0.f);
    }
    if (tid == 0) out[O_TRIP] = trip / 64.f;
}

// ---------------- right half of F_M, all f32 VALU ----------------
// NHALF=1: rows 0..32767  -> nnew + A_Naug_mu, plus kl
// NHALF=0: rows 32768..   -> A_aug_new + N_Aaug_mu
template <int NHALF>
__global__ __launch_bounds__(256) void k_right(const float* __restrict__ att, const float* __restrict__ pam,
                                               const float* __restrict__ pnm, const float* __restrict__ pnv,
                                               const float* __restrict__ bmu, const float* __restrict__ bvar,
                                               const float* __restrict__ epsv, float* __restrict__ fm,
                                               float* __restrict__ klacc) {
    __shared__ float attL[64][129];
    __shared__ float pa[32][64];
    __shared__ float pn[32][64];
    __shared__ float pv[32][64];
    __shared__ float red[8];
    int tid = threadIdx.x;
    int row0 = blockIdx.x * 64 + (NHALF ? 0 : 32768);

    // stage att rows [64][128]
    #pragma unroll
    for (int j = 0; j < 8; ++j) {
        int ix = tid + j * 256;
        int rr = ix >> 5, c4 = ix & 31;
        f32x4 v = *(const f32x4*)&att[(size_t)(row0 + rr) * 128 + c4 * 4];
        attL[rr][c4 * 4 + 0] = v.x; attL[rr][c4 * 4 + 1] = v.y;
        attL[rr][c4 * 4 + 2] = v.z; attL[rr][c4 * 4 + 3] = v.w;
    }

    int ty = tid >> 3, tx = tid & 7;   // rows ty*2..+1, cols tx*8..+7 (within 64-col chunk)
    float kll = 0.f;
    for (int nc = 0; nc < 8; ++nc) {
        int n0 = nc * 64;
        float accA[2][8], accN[2][8], accV[2][8];
        #pragma unroll
        for (int r = 0; r < 2; ++r)
            #pragma unroll
            for (int j = 0; j < 8; ++j) { accA[r][j] = 0.f; accN[r][j] = 0.f; accV[r][j] = 0.f; }

        #pragma unroll
        for (int kh = 0; kh < 2; ++kh) {
            __syncthreads();
            #pragma unroll
            for (int j = 0; j < 2; ++j) {
                int ix = tid + j * 256;
                int kr = ix >> 4, c4 = ix & 15;
                *(f32x4*)&pa[kr][c4 * 4] = *(const f32x4*)&pam[(size_t)(kh * 32 + kr) * 512 + n0 + c4 * 4];
                *(f32x4*)&pn[kr][c4 * 4] = *(const f32x4*)&pnm[(size_t)(kh * 32 + kr) * 512 + n0 + c4 * 4];
                if (NHALF)
                    *(f32x4*)&pv[kr][c4 * 4] = *(const f32x4*)&pnv[(size_t)(kh * 32 + kr) * 512 + n0 + c4 * 4];
            }
            __syncthreads();
            for (int k = 0; k < 32; ++k) {
                float a0 = attL[ty * 2][kh * 32 + k];
                float a1 = attL[ty * 2 + 1][kh * 32 + k];
                float b0 = attL[ty * 2][64 + kh * 32 + k];
                float b1 = attL[ty * 2 + 1][64 + kh * 32 + k];
                #pragma unroll
                for (int j = 0; j < 8; ++j) {
                    float pav = pa[k][tx * 8 + j];
                    float pnv_ = pn[k][tx * 8 + j];
                    accA[0][j] += a0 * pav;  accA[1][j] += a1 * pav;
                    accN[0][j] += b0 * pnv_; accN[1][j] += b1 * pnv_;
                    if (NHALF) {
                        float pvv = pv[k][tx * 8 + j];
                        accV[0][j] += b0 * pvv; accV[1][j] += b1 * pvv;
                    }
                }
            }
        }
        // epilogue for this 64-col chunk
        #pragma unroll
        for (int r = 0; r < 2; ++r) {
            int row = row0 + ty * 2 + r;
            #pragma unroll
            for (int j = 0; j < 8; ++j) {
                int col = n0 + tx * 8 + j;
                float v;
                if (NHALF) {
                    float mu = accN[r][j] + bmu[col];
                    float var = accV[r][j] + bvar[col];
                    float ev = expf(var);
                    v = mu + epsv[(size_t)row * 512 + col] * sqrtf(ev) + accA[r][j] + bmu[col];
                    kll += 1.f + var - mu * mu - ev;
                } else {
                    v = accA[r][j] + accN[r][j] + 2.f * bmu[col];
                }
                fm[(size_t)row * 1024 + 512 + col] = v;
            }
        }
    }
    if (NHALF) {
        __syncthreads();
        float s = blk_sum(kll, red);
        if (tid == 0) atomicAdd(klacc, s);
    }
}

// ---------------- anchor norms: recompute pure nnew (f32) for gathered rows ----------------
__global__ __launch_bounds__(256) void k_gather2a(const int* __restrict__ idx, const float* __restrict__ att,
                                                  const float* __restrict__ pnm, const float* __restrict__ pnv,
                                                  const float* __restrict__ bmu, const float* __restrict__ bvar,
                                                  const float* __restrict__ epsv, float* __restrict__ norms) {
    __shared__ float arow[64];
    __shared__ float red[8];
    int b = blockIdx.x, tid = threadIdx.x;
    float s0 = 0.f, s1 = 0.f;
    for (int i = 0; i < 33; ++i) {
        int t = idx[(64 + b) * 40 + i];   // N_idx
        size_t r = (size_t)b * 512 + t;
        __syncthreads();
        if (tid < 64) arow[tid] = att[r * 128 + 64 + tid];
        __syncthreads();
        float mu0 = bmu[tid], mu1 = bmu[tid + 256];
        float v0 = bvar[tid], v1 = bvar[tid + 256];
        for (int k = 0; k < 64; ++k) {
            float a = arow[k];
            mu0 += a * pnm[(size_t)k * 512 + tid];
            mu1 += a * pnm[(size_t)k * 512 + tid + 256];
            v0  += a * pnv[(size_t)k * 512 + tid];
            v1  += a * pnv[(size_t)k * 512 + tid + 256];
        }
        s0 += mu0 + epsv[r * 512 + tid]       * sqrtf(expf(v0));
        s1 += mu1 + epsv[r * 512 + tid + 256] * sqrtf(expf(v1));
    }
    s0 *= (1.f / 33.f); s1 *= (1.f / 33.f);
    float ss = blk_sum(s0 * s0 + s1 * s1, red);
    if (tid == 0) norms[b] = sqrtf(ss);
}

// ---------------- negative norms: mean-att @ P_A_mu + b_mu (linearity) ----------------
__global__ __launch_bounds__(256) void k_gather2b(const int* __restrict__ idx, const float* __restrict__ att,
                                                  const float* __restrict__ pam, const float* __restrict__ bmu,
                                                  float* __restrict__ norms) {
    __shared__ float meanA[64];
    __shared__ float red[8];
    int b = blockIdx.x, tid = threadIdx.x;
    if (tid < 64) {
        float s = 0.f;
        for (int i = 0; i < 33; ++i) {
            int t = idx[b * 40 + i];      // A_idx
            s += att[(size_t)(32768 + b * 512 + t) * 128 + tid];
        }
        meanA[tid] = s * (1.f / 33.f);
    }
    __syncthreads();
    float s0 = bmu[tid], s1 = bmu[tid + 256];
    #pragma unroll 4
    for (int k = 0; k < 64; ++k) {
        float m = meanA[k];
        s0 += m * pam[(size_t)k * 512 + tid];
        s1 += m * pam[(size_t)k * 512 + tid + 256];
    }
    float ss = blk_sum(s0 * s0 + s1 * s1, red);
    if (tid == 0) norms[64 + b] = sqrtf(ss);
}

// ---------------- finalize: distance + kl ----------------
__global__ __launch_bounds__(64) void k_final(const float* __restrict__ norms, const float* __restrict__ klacc,
                                              float* __restrict__ out) {
    int tid = threadIdx.x;
    float v = fmaxf(100.f - norms[64 + tid] + norms[tid], 0.f);
    #pragma unroll
    for (int o = 32; o; o >>= 1) v += __shfl_xor(v, o);
    if (tid == 0) {
        out[O_DIST] = v / 64.f;
        out[O_KL]   = -0.5f * (*klacc) / 32768.f;
    }
}

extern "C" void kernel_launch(void* const* d_in, const int* in_sizes, int n_in,
                              void* d_out, int out_size, void* d_ws, size_t ws_size,
                              hipStream_t stream) {
    const float* x    = (const float*)d_in[0];
    const float* Amem = (const float*)d_in[1];
    const float* Nmem = (const float*)d_in[2];
    const float* Wmu  = (const float*)d_in[3];
    const float* bmu  = (const float*)d_in[4];
    const float* Wvar = (const float*)d_in[5];
    const float* bvar = (const float*)d_in[6];
    const float* eps  = (const float*)d_in[7];
    float* out = (float*)d_out;
    char* ws = (char*)d_ws;
    const float* att = (const float*)(ws + WS_ATT);
    const float* pam = (const float*)(ws + WS_PAM);
    const float* pnm = (const float*)(ws + WS_PNM);
    const float* pnv = (const float*)(ws + WS_PNV);
    const int* idx   = (const int*)(ws + WS_IDX);

    k_prep<<<256, 256, 0, stream>>>(Amem, Nmem, ws);
    k_proj<<<192, 256, 0, stream>>>(Amem, Nmem, Wmu, Wvar,
                                    (float*)(ws + WS_PAM), (float*)(ws + WS_PNM), (float*)(ws + WS_PNV));
    k_dots<<<1024, 256, 0, stream>>>(x, ws, out);
    k_topk<<<192, 256, 0, stream>>>((const float*)(ws + WS_TATT), (int*)(ws + WS_IDX));
    k_gather3<<<64, 256, 0, stream>>>(x, idx, (float*)(ws + WS_GATH));
    k_triplet<<<1, 256, 0, stream>>>((const float*)(ws + WS_GATH), out);
    k_right<1><<<512, 256, 0, stream>>>(att, pam, pnm, pnv, bmu, bvar, eps, out, (float*)(ws + WS_KL));
    k_right<0><<<512, 256, 0, stream>>>(att, pam, pnm, pnv, bmu, bvar, eps, out, (float*)(ws + WS_KL));
    k_gather2a<<<64, 256, 0, stream>>>(idx, att, pnm, pnv, bmu, bvar, eps, (float*)(ws + WS_NORM));
    k_gather2b<<<64, 256, 0, stream>>>(idx, att, pam, bmu, (float*)(ws + WS_NORM));
    k_final<<<1, 64, 0, stream>>>((const float*)(ws + WS_NORM), (const float*)(ws + WS_KL), out);
}

// Round 9
// 605.589 us; speedup vs baseline: 1.1823x; 1.1823x over previous
//
#include <hip/hip_runtime.h>
#include <hip/hip_bf16.h>
#include <math.h>

// B=128, T=512, D=512, K=64; mid=64; rows per half = 32768. f32 in/out.
typedef unsigned short u16;
typedef __attribute__((ext_vector_type(4))) float f32x4;
typedef __attribute__((ext_vector_type(8))) short s16x8;

// ---------------- output offsets (f32 elements) ----------------
#define O_FM    0ULL
#define O_TRIP  67108864ULL
#define O_KL    67108865ULL
#define O_DIST  67108866ULL
#define O_AATT  67108867ULL
#define O_NATT  67141635ULL
#define O_ANATT 67174403ULL
#define O_NAATT 67207171ULL

// ---------------- ws offsets (bytes), total ~18.45 MB (<= 35 MB proven safe) ----
#define WS_ATTB  0ULL          // att bf16 [65536][128] (k<64: vs Amem, k>=64: vs Nmem)
#define WS_BCT   16777216ULL   // bf16 [512 n][128 k]: k<64 = pam^T, k>=64 = pnm^T
#define WS_PVT   16908288ULL   // bf16 [512 n][64 k] = pnv^T
#define WS_PAM   16973824ULL   // f32 [64][512]  (Amem @ W_mu)
#define WS_PNM   17104896ULL   // f32 [64][512]  (Nmem @ W_mu)
#define WS_PNV   17235968ULL   // f32 [64][512]  (Nmem @ W_var)
#define WS_MEMT  17367040ULL   // f32 [512][128] (memT[d][k], k<64:Amem else Nmem)
#define WS_TATT  17629184ULL   // f32 [3][32768] (0=A_att,1=N_att,2=N_Aatt)
#define WS_IDX   18022400ULL   // int [3][64][40]
#define WS_GATH  18053120ULL   // f32 [3][64][512]
#define WS_NORM  18446336ULL   // f32 [128]
#define WS_KL    18446848ULL   // f32 accumulator

__device__ __forceinline__ u16 f2bf(float f) {
    union { float f; unsigned int u; } c; c.f = f;
    unsigned int r = c.u + 0x7fffu + ((c.u >> 16) & 1u);
    return (u16)(r >> 16);
}
__device__ __forceinline__ float bf2f(u16 h) {
    union { unsigned int u; float f; } c; c.u = ((unsigned int)h) << 16;
    return c.f;
}

__device__ __forceinline__ float blk_sum(float v, float* red) {
    #pragma unroll
    for (int o = 32; o; o >>= 1) v += __shfl_xor(v, o);
    int tid = threadIdx.x;
    if ((tid & 63) == 0) red[tid >> 6] = v;
    __syncthreads();
    float r = red[0] + red[1] + red[2] + red[3];
    __syncthreads();
    return r;
}

// stage a 128x32 bf16 tile into LDS linearly -- 512-thread version (one 16B load each)
__device__ __forceinline__ void stage32_512(const u16* __restrict__ g, int row0, int ld, int k0,
                                            u16* s, int tid) {
    const u16* src = g + (size_t)(row0 + (tid >> 2)) * ld + k0 + (tid & 3) * 8;
    __builtin_amdgcn_global_load_lds((const __attribute__((address_space(1))) void*)src,
                                     (__attribute__((address_space(3))) void*)(s + tid * 8),
                                     16, 0, 0);
}

// ---------------- prep: memT transpose + kl zero ----------------
__global__ __launch_bounds__(256) void k_prep(const float* __restrict__ Amem, const float* __restrict__ Nmem,
                                              char* __restrict__ ws) {
    int i = blockIdx.x * 256 + threadIdx.x;
    if (i == 0) *(float*)(ws + WS_KL) = 0.f;
    int d = i >> 7, k = i & 127;
    float v = (k < 64) ? Amem[(size_t)k * 512 + d] : Nmem[(size_t)(k - 64) * 512 + d];
    ((float*)(ws + WS_MEMT))[i] = v;
}

// ---------------- proj: P = mem @ W, f32 [k][n] + bf16 transposed ----------------
__global__ __launch_bounds__(256) void k_proj(const float* __restrict__ Amem, const float* __restrict__ Nmem,
                                              const float* __restrict__ Wmu, const float* __restrict__ Wvar,
                                              float* __restrict__ pam, float* __restrict__ pnm,
                                              float* __restrict__ pnv, u16* __restrict__ bct,
                                              u16* __restrict__ pvt) {
    __shared__ float mr[512];
    int mat = blockIdx.x >> 6, k = blockIdx.x & 63, tid = threadIdx.x;
    const float* mrow = ((mat == 0) ? Amem : Nmem) + (size_t)k * 512;
    const float* W = (mat == 2) ? Wvar : Wmu;
    mr[tid] = mrow[tid]; mr[tid + 256] = mrow[tid + 256];
    __syncthreads();
    float s0 = 0.f, s1 = 0.f;
    for (int d = 0; d < 512; ++d) {
        float m = mr[d];
        s0 += m * W[(size_t)d * 512 + tid];
        s1 += m * W[(size_t)d * 512 + tid + 256];
    }
    if (mat == 0) {
        pam[(size_t)k * 512 + tid] = s0; pam[(size_t)k * 512 + tid + 256] = s1;
        bct[(size_t)tid * 128 + k] = f2bf(s0); bct[(size_t)(tid + 256) * 128 + k] = f2bf(s1);
    } else if (mat == 1) {
        pnm[(size_t)k * 512 + tid] = s0; pnm[(size_t)k * 512 + tid + 256] = s1;
        bct[(size_t)tid * 128 + 64 + k] = f2bf(s0); bct[(size_t)(tid + 256) * 128 + 64 + k] = f2bf(s1);
    } else {
        pnv[(size_t)k * 512 + tid] = s0; pnv[(size_t)k * 512 + tid + 256] = s1;
        pvt[(size_t)tid * 64 + k] = f2bf(s0); pvt[(size_t)(tid + 256) * 64 + k] = f2bf(s1);
    }
}

// ---------------- dots: att bf16, sigmoid, t_att top5, x->F_M left (f32 copy) ----------------
__global__ __launch_bounds__(256) void k_dots(const float* __restrict__ x, char* __restrict__ ws,
                                              float* __restrict__ out) {
    __shared__ float xs[64][66];
    __shared__ char smem[64 * 128 * 4];
    float (*ms)[128]   = (float(*)[128])smem;
    float (*attl)[128] = (float(*)[128])smem;

    int tid = threadIdx.x;
    int row0 = blockIdx.x * 64;
    const float* memT = (const float*)(ws + WS_MEMT);
    u16* attb = (u16*)(ws + WS_ATTB);
    int ty = tid >> 4, tx = tid & 15;

    float acc[4][8];
    #pragma unroll
    for (int r = 0; r < 4; ++r)
        #pragma unroll
        for (int j = 0; j < 8; ++j) acc[r][j] = 0.f;

    for (int dc = 0; dc < 8; ++dc) {
        int d0 = dc * 64;
        {   // stage x tile + exact f32 copy into F_M left half
            int rr = tid >> 2, q = tid & 3;
            const float* src = x + (size_t)(row0 + rr) * 512 + d0 + q * 16;
            float* dst = out + (size_t)(row0 + rr) * 1024 + d0 + q * 16;
            #pragma unroll
            for (int j = 0; j < 4; ++j) {
                f32x4 v = *(const f32x4*)(src + j * 4);
                *(f32x4*)(dst + j * 4) = v;
                xs[rr][q * 16 + j * 4 + 0] = v.x; xs[rr][q * 16 + j * 4 + 1] = v.y;
                xs[rr][q * 16 + j * 4 + 2] = v.z; xs[rr][q * 16 + j * 4 + 3] = v.w;
            }
        }
        {   // stage memT chunk [64][128]
            const f32x4* src = (const f32x4*)(memT + (size_t)d0 * 128);
            f32x4* dstv = (f32x4*)&ms[0][0];
            #pragma unroll
            for (int j = 0; j < 8; ++j) dstv[tid + j * 256] = src[tid + j * 256];
        }
        __syncthreads();
        #pragma unroll 2
        for (int d = 0; d < 64; ++d) {
            f32x4 mlo = *(const f32x4*)&ms[d][tx * 8];
            f32x4 mhi = *(const f32x4*)&ms[d][tx * 8 + 4];
            #pragma unroll
            for (int r = 0; r < 4; ++r) {
                float xv = xs[ty * 4 + r][d];
                acc[r][0] += xv * mlo.x; acc[r][1] += xv * mlo.y;
                acc[r][2] += xv * mlo.z; acc[r][3] += xv * mlo.w;
                acc[r][4] += xv * mhi.x; acc[r][5] += xv * mhi.y;
                acc[r][6] += xv * mhi.z; acc[r][7] += xv * mhi.w;
            }
        }
        __syncthreads();
    }

    // sigmoid -> att bf16 (ws) + f32 LDS for t_att
    #pragma unroll
    for (int r = 0; r < 4; ++r) {
        u16* bp = attb + (size_t)(row0 + ty * 4 + r) * 128 + tx * 8;
        #pragma unroll
        for (int j = 0; j < 8; ++j) {
            float logit = acc[r][j] * 0.044194173824159216f;  // 1/sqrt(512)
            float av = 1.f / (1.f + expf(-logit));
            attl[ty * 4 + r][tx * 8 + j] = av;
            bp[j] = f2bf(av);
        }
    }
    __syncthreads();

    // t_att: top-5-of-64 via reduce-max + ballot knockout
    int lane = tid & 63, w = tid >> 6;
    float* tatt = (float*)(ws + WS_TATT);
    int half = row0 >> 15;
    for (int rr = 0; rr < 16; ++rr) {
        int r = w * 16 + rr;
        int lr = (row0 + r) & 32767;
        #pragma unroll
        for (int side = 0; side < 2; ++side) {
            float cur = attl[r][side * 64 + lane];
            float sum5 = 0.f;
            #pragma unroll
            for (int it = 0; it < 5; ++it) {
                float m = cur;
                #pragma unroll
                for (int o = 32; o; o >>= 1) { float t = __shfl_xor(m, o); m = fmaxf(m, t); }
                sum5 += m;
                unsigned long long bl = __ballot(cur == m);
                int srcl = __ffsll(bl) - 1;
                if (lane == srcl) cur = -INFINITY;
            }
            if (lane == 0) {
                float tv = sum5 / 5.f;
                if (half) {
                    if (side == 0) { out[O_AATT + lr]  = tv; tatt[lr] = tv; }
                    else           { out[O_NAATT + lr] = tv; tatt[2 * 32768 + lr] = tv; }
                } else {
                    if (side == 0) { out[O_ANATT + lr] = tv; }
                    else           { out[O_NATT + lr]  = tv; tatt[32768 + lr] = tv; }
                }
            }
        }
    }
}

// ---------------- top-33 over t for 3 matrices ----------------
__global__ __launch_bounds__(256) void k_topk(const float* __restrict__ tatt, int* __restrict__ idx) {
    __shared__ float vals[512];
    __shared__ float rv[256];
    __shared__ int   ri[256];
    int s = blockIdx.x >> 6;
    int b = blockIdx.x & 63;
    int tid = threadIdx.x;
    const float* src = tatt + (size_t)s * 32768 + b * 512;
    vals[tid] = src[tid]; vals[tid + 256] = src[tid + 256];
    __syncthreads();
    for (int it = 0; it < 33; ++it) {
        float a = vals[tid]; int ia = tid;
        float c = vals[tid + 256];
        if (c > a) { a = c; ia = tid + 256; }
        rv[tid] = a; ri[tid] = ia;
        __syncthreads();
        for (int st = 128; st > 0; st >>= 1) {
            if (tid < st) {
                float o = rv[tid + st]; int oi = ri[tid + st];
                if (o > rv[tid] || (o == rv[tid] && oi < ri[tid])) { rv[tid] = o; ri[tid] = oi; }
            }
            __syncthreads();
        }
        if (tid == 0) { idx[(s * 64 + b) * 40 + it] = ri[0]; vals[ri[0]] = -INFINITY; }
        __syncthreads();
    }
}

// ---------------- gather means of x over the 3 index sets ----------------
__global__ __launch_bounds__(256) void k_gather3(const float* __restrict__ x, const int* __restrict__ idx,
                                                 float* __restrict__ gath) {
    int b = blockIdx.x, tid = threadIdx.x;
    int d0 = tid * 2;
    #pragma unroll
    for (int s = 0; s < 3; ++s) {
        int srcb = (s == 1) ? b : 64 + b;
        const float* xb = x + (size_t)srcb * 512 * 512;
        float a0 = 0.f, a1 = 0.f;
        for (int i = 0; i < 33; ++i) {
            int t = idx[(s * 64 + b) * 40 + i];
            const float* p = xb + (size_t)t * 512 + d0;
            a0 += p[0]; a1 += p[1];
        }
        gath[((size_t)s * 64 + b) * 512 + d0]     = a0 / 33.f;
        gath[((size_t)s * 64 + b) * 512 + d0 + 1] = a1 / 33.f;
    }
}

// ---------------- triplet ----------------
__global__ __launch_bounds__(256) void k_triplet(const float* __restrict__ gath, float* __restrict__ out) {
    __shared__ float red[8];
    int tid = threadIdx.x;
    float trip = 0.f;
    for (int b = 0; b < 64; ++b) {
        const float* a = gath + (size_t)(64 + b) * 512;   // anchor
        const float* p = gath + (size_t)(128 + b) * 512;  // positive
        const float* n = gath + (size_t)(b) * 512;        // negative
        float a0 = a[tid], a1 = a[tid + 256];
        float p0 = p[tid], p1 = p[tid + 256];
        float n0 = n[tid], n1 = n[tid + 256];
        float na  = sqrtf(blk_sum(a0 * a0 + a1 * a1, red));
        float npv = sqrtf(blk_sum(p0 * p0 + p1 * p1, red));
        float nn  = sqrtf(blk_sum(n0 * n0 + n1 * n1, red));
        float e0 = a0 / na - p0 / npv + 1e-6f, e1 = a1 / na - p1 / npv + 1e-6f;
        float f0 = a0 / na - n0 / nn  + 1e-6f, f1 = a1 / na - n1 / nn  + 1e-6f;
        float dap = sqrtf(blk_sum(e0 * e0 + e1 * e1, red));
        float dan = sqrtf(blk_sum(f0 * f0 + f1 * f1, red));
        if (tid == 0) trip += fmaxf(dap - dan + 1.f, 0.f);
    }
    if (tid == 0) out[O_TRIP] = trip / 64.f;
}

// ---------------- G1: N-half right F_M via MFMA (3 GEMMs K=64) + kl. 512 threads ----------------
__global__ __launch_bounds__(512) void kG1(const u16* __restrict__ attb, const u16* __restrict__ bct,
                                           const u16* __restrict__ pvt, const float* __restrict__ bmu,
                                           const float* __restrict__ bvar, const float* __restrict__ epsv,
                                           float* __restrict__ fm, float* __restrict__ klacc) {
    __shared__ u16 sAA[128 * 32];
    __shared__ u16 sAN[128 * 32];
    __shared__ u16 sBA[128 * 32];
    __shared__ u16 sBN[128 * 32];
    __shared__ u16 sBV[128 * 32];
    __shared__ float red[8];
    int tid = threadIdx.x, lane = tid & 63, wid = tid >> 6;
    int wr = wid >> 2, wc = wid & 3;            // 8 waves: 2 x 4; wave tile 64 rows x 32 cols
    int cl = lane & 15, rq = lane >> 4;
    int m0 = blockIdx.x * 128, c0 = blockIdx.y * 128;

    f32x4 aA[4][2], aN[4][2], aV[4][2];
    #pragma unroll
    for (int i = 0; i < 4; ++i)
        #pragma unroll
        for (int j = 0; j < 2; ++j) { aA[i][j] = (f32x4)0.f; aN[i][j] = (f32x4)0.f; aV[i][j] = (f32x4)0.f; }

    for (int kt = 0; kt < 2; ++kt) {
        stage32_512(attb, m0, 128, kt * 32, sAA, tid);
        stage32_512(attb, m0, 128, 64 + kt * 32, sAN, tid);
        stage32_512(bct, c0, 128, kt * 32, sBA, tid);
        stage32_512(bct, c0, 128, 64 + kt * 32, sBN, tid);
        stage32_512(pvt, c0, 64, kt * 32, sBV, tid);
        __syncthreads();
        s16x8 fA[4], fN[4], bA[2], bN[2], bV[2];
        #pragma unroll
        for (int i = 0; i < 4; ++i) {
            fA[i] = *(const s16x8*)&sAA[(wr * 64 + i * 16 + cl) * 32 + rq * 8];
            fN[i] = *(const s16x8*)&sAN[(wr * 64 + i * 16 + cl) * 32 + rq * 8];
        }
        #pragma unroll
        for (int n = 0; n < 2; ++n) {
            bA[n] = *(const s16x8*)&sBA[(wc * 32 + n * 16 + cl) * 32 + rq * 8];
            bN[n] = *(const s16x8*)&sBN[(wc * 32 + n * 16 + cl) * 32 + rq * 8];
            bV[n] = *(const s16x8*)&sBV[(wc * 32 + n * 16 + cl) * 32 + rq * 8];
        }
        #pragma unroll
        for (int mi = 0; mi < 4; ++mi)
            #pragma unroll
            for (int ni = 0; ni < 2; ++ni) {
                aA[mi][ni] = __builtin_amdgcn_mfma_f32_16x16x32_bf16(fA[mi], bA[ni], aA[mi][ni], 0, 0, 0);
                aN[mi][ni] = __builtin_amdgcn_mfma_f32_16x16x32_bf16(fN[mi], bN[ni], aN[mi][ni], 0, 0, 0);
                aV[mi][ni] = __builtin_amdgcn_mfma_f32_16x16x32_bf16(fN[mi], bV[ni], aV[mi][ni], 0, 0, 0);
            }
        __syncthreads();
    }

    float kll = 0.f;
    #pragma unroll
    for (int mi = 0; mi < 4; ++mi)
        #pragma unroll
        for (int ni = 0; ni < 2; ++ni) {
            int col = c0 + wc * 32 + ni * 16 + cl;
            int rowb = m0 + wr * 64 + mi * 16 + rq * 4;
            float bm = bmu[col], bv = bvar[col];
            #pragma unroll
            for (int q = 0; q < 4; ++q) {
                int row = rowb + q;
                float muN = aN[mi][ni][q] + bm;
                float var = aV[mi][ni][q] + bv;
                float ev = expf(var);
                float muA = aA[mi][ni][q] + bm;
                fm[(size_t)row * 1024 + 512 + col] =
                    muN + epsv[(size_t)row * 512 + col] * sqrtf(ev) + muA;
                kll += 1.f + var - muN * muN - ev;
            }
        }
    #pragma unroll
    for (int o = 32; o; o >>= 1) kll += __shfl_xor(kll, o);
    if (lane == 0) red[wid] = kll;
    __syncthreads();
    if (tid == 0) {
        float s = 0.f;
        #pragma unroll
        for (int i = 0; i < 8; ++i) s += red[i];
        atomicAdd(klacc, s);
    }
}

// ---------------- G3: A-half right F_M via MFMA (K=128). 512 threads ----------------
__global__ __launch_bounds__(512) void kG3(const u16* __restrict__ attb, const u16* __restrict__ bct,
                                           const float* __restrict__ bmu, float* __restrict__ fm) {
    __shared__ u16 sA[128 * 32];
    __shared__ u16 sB[128 * 32];
    int tid = threadIdx.x, lane = tid & 63, wid = tid >> 6;
    int wr = wid >> 2, wc = wid & 3;
    int cl = lane & 15, rq = lane >> 4;
    int m0 = blockIdx.x * 128, c0 = blockIdx.y * 128;

    f32x4 acc[4][2];
    #pragma unroll
    for (int i = 0; i < 4; ++i)
        #pragma unroll
        for (int j = 0; j < 2; ++j) acc[i][j] = (f32x4)0.f;

    for (int kt = 0; kt < 4; ++kt) {
        stage32_512(attb, 32768 + m0, 128, kt * 32, sA, tid);
        stage32_512(bct, c0, 128, kt * 32, sB, tid);
        __syncthreads();
        s16x8 fa[4], fb[2];
        #pragma unroll
        for (int i = 0; i < 4; ++i)
            fa[i] = *(const s16x8*)&sA[(wr * 64 + i * 16 + cl) * 32 + rq * 8];
        #pragma unroll
        for (int n = 0; n < 2; ++n)
            fb[n] = *(const s16x8*)&sB[(wc * 32 + n * 16 + cl) * 32 + rq * 8];
        #pragma unroll
        for (int mi = 0; mi < 4; ++mi)
            #pragma unroll
            for (int ni = 0; ni < 2; ++ni)
                acc[mi][ni] = __builtin_amdgcn_mfma_f32_16x16x32_bf16(fa[mi], fb[ni], acc[mi][ni], 0, 0, 0);
        __syncthreads();
    }
    #pragma unroll
    for (int mi = 0; mi < 4; ++mi)
        #pragma unroll
        for (int ni = 0; ni < 2; ++ni) {
            int col = c0 + wc * 32 + ni * 16 + cl;
            int rowb = 32768 + m0 + wr * 64 + mi * 16 + rq * 4;
            float bm2 = 2.f * bmu[col];
            #pragma unroll
            for (int q = 0; q < 4; ++q)
                fm[(size_t)(rowb + q) * 1024 + 512 + col] = acc[mi][ni][q] + bm2;
        }
}

// ---------------- anchor norms: recompute pure nnew (f32) for gathered rows ----------------
__global__ __launch_bounds__(256) void k_gather2a(const int* __restrict__ idx, const u16* __restrict__ attb,
                                                  const float* __restrict__ pnm, const float* __restrict__ pnv,
                                                  const float* __restrict__ bmu, const float* __restrict__ bvar,
                                                  const float* __restrict__ epsv, float* __restrict__ norms) {
    __shared__ float arow[64];
    __shared__ float red[8];
    int b = blockIdx.x, tid = threadIdx.x;
    float s0 = 0.f, s1 = 0.f;
    for (int i = 0; i < 33; ++i) {
        int t = idx[(64 + b) * 40 + i];   // N_idx
        size_t r = (size_t)b * 512 + t;
        __syncthreads();
        if (tid < 64) arow[tid] = bf2f(attb[r * 128 + 64 + tid]);
        __syncthreads();
        float mu0 = bmu[tid], mu1 = bmu[tid + 256];
        float v0 = bvar[tid], v1 = bvar[tid + 256];
        for (int k = 0; k < 64; ++k) {
            float a = arow[k];
            mu0 += a * pnm[(size_t)k * 512 + tid];
            mu1 += a * pnm[(size_t)k * 512 + tid + 256];
            v0  += a * pnv[(size_t)k * 512 + tid];
            v1  += a * pnv[(size_t)k * 512 + tid + 256];
        }
        s0 += mu0 + epsv[r * 512 + tid]       * sqrtf(expf(v0));
        s1 += mu1 + epsv[r * 512 + tid + 256] * sqrtf(expf(v1));
    }
    s0 *= (1.f / 33.f); s1 *= (1.f / 33.f);
    float ss = blk_sum(s0 * s0 + s1 * s1, red);
    if (tid == 0) norms[b] = sqrtf(ss);
}

// ---------------- negative norms: mean-att @ P_A_mu + b_mu (linearity) ----------------
__global__ __launch_bounds__(256) void k_gather2b(const int* __restrict__ idx, const u16* __restrict__ attb,
                                                  const float* __restrict__ pam, const float* __restrict__ bmu,
                                                  float* __restrict__ norms) {
    __shared__ float meanA[64];
    __shared__ float red[8];
    int b = blockIdx.x, tid = threadIdx.x;
    if (tid < 64) {
        float s = 0.f;
        for (int i = 0; i < 33; ++i) {
            int t = idx[b * 40 + i];      // A_idx
            s += bf2f(attb[(size_t)(32768 + b * 512 + t) * 128 + tid]);
        }
        meanA[tid] = s * (1.f / 33.f);
    }
    __syncthreads();
    float s0 = bmu[tid], s1 = bmu[tid + 256];
    #pragma unroll 4
    for (int k = 0; k < 64; ++k) {
        float m = meanA[k];
        s0 += m * pam[(size_t)k * 512 + tid];
        s1 += m * pam[(size_t)k * 512 + tid + 256];
    }
    float ss = blk_sum(s0 * s0 + s1 * s1, red);
    if (tid == 0) norms[64 + b] = sqrtf(ss);
}

// ---------------- finalize: distance + kl ----------------
__global__ __launch_bounds__(64) void k_final(const float* __restrict__ norms, const float* __restrict__ klacc,
                                              float* __restrict__ out) {
    int tid = threadIdx.x;
    float v = fmaxf(100.f - norms[64 + tid] + norms[tid], 0.f);
    #pragma unroll
    for (int o = 32; o; o >>= 1) v += __shfl_xor(v, o);
    if (tid == 0) {
        out[O_DIST] = v / 64.f;
        out[O_KL]   = -0.5f * (*klacc) / 32768.f;
    }
}

extern "C" void kernel_launch(void* const* d_in, const int* in_sizes, int n_in,
                              void* d_out, int out_size, void* d_ws, size_t ws_size,
                              hipStream_t stream) {
    const float* x    = (const float*)d_in[0];
    const float* Amem = (const float*)d_in[1];
    const float* Nmem = (const float*)d_in[2];
    const float* Wmu  = (const float*)d_in[3];
    const float* bmu  = (const float*)d_in[4];
    const float* Wvar = (const float*)d_in[5];
    const float* bvar = (const float*)d_in[6];
    const float* eps  = (const float*)d_in[7];
    float* out = (float*)d_out;
    char* ws = (char*)d_ws;
    const u16* attb  = (const u16*)(ws + WS_ATTB);
    const u16* bct   = (const u16*)(ws + WS_BCT);
    const u16* pvt   = (const u16*)(ws + WS_PVT);
    const float* pam = (const float*)(ws + WS_PAM);
    const float* pnm = (const float*)(ws + WS_PNM);
    const float* pnv = (const float*)(ws + WS_PNV);
    const int* idx   = (const int*)(ws + WS_IDX);

    k_prep<<<256, 256, 0, stream>>>(Amem, Nmem, ws);
    k_proj<<<192, 256, 0, stream>>>(Amem, Nmem, Wmu, Wvar,
                                    (float*)(ws + WS_PAM), (float*)(ws + WS_PNM), (float*)(ws + WS_PNV),
                                    (u16*)(ws + WS_BCT), (u16*)(ws + WS_PVT));
    k_dots<<<1024, 256, 0, stream>>>(x, ws, out);
    k_topk<<<192, 256, 0, stream>>>((const float*)(ws + WS_TATT), (int*)(ws + WS_IDX));
    k_gather3<<<64, 256, 0, stream>>>(x, idx, (float*)(ws + WS_GATH));
    k_triplet<<<1, 256, 0, stream>>>((const float*)(ws + WS_GATH), out);
    kG1<<<dim3(256, 4), 512, 0, stream>>>(attb, bct, pvt, bmu, bvar, eps, out, (float*)(ws + WS_KL));
    kG3<<<dim3(256, 4), 512, 0, stream>>>(attb, bct, bmu, out);
    k_gather2a<<<64, 256, 0, stream>>>(idx, attb, pnm, pnv, bmu, bvar, eps, (float*)(ws + WS_NORM));
    k_gather2b<<<64, 256, 0, stream>>>(idx, attb, pam, bmu, (float*)(ws + WS_NORM));
    k_final<<<1, 64, 0, stream>>>((const float*)(ws + WS_NORM), (const float*)(ws + WS_KL), out);
}

// Round 10
// 406.669 us; speedup vs baseline: 1.7606x; 1.4891x over previous
//
#include <hip/hip_runtime.h>
#include <hip/hip_bf16.h>
#include <math.h>

// B=128, T=512, D=512, K=64; mid=64; rows per half = 32768. f32 in/out.
typedef unsigned short u16;
typedef __attribute__((ext_vector_type(4))) float f32x4;
typedef __attribute__((ext_vector_type(8))) short s16x8;

// ---------------- output offsets (f32 elements) ----------------
#define O_FM    0ULL
#define O_TRIP  67108864ULL
#define O_KL    67108865ULL
#define O_DIST  67108866ULL
#define O_AATT  67108867ULL
#define O_NATT  67141635ULL
#define O_ANATT 67174403ULL
#define O_NAATT 67207171ULL

// ---------------- ws offsets (bytes), total ~18.6 MB (<= 35 MB proven safe) ----
#define WS_ATTB  0ULL          // att bf16 [65536][128] (k<64: vs Amem, k>=64: vs Nmem)
#define WS_BCT   16777216ULL   // bf16 [512 n][128 k]: k<64 = pam^T, k>=64 = pnm^T
#define WS_PVT   16908288ULL   // bf16 [512 n][64 k] = pnv^T
#define WS_PAM   16973824ULL   // f32 [64][512]  (Amem @ W_mu)
#define WS_PNM   17104896ULL   // f32 [64][512]  (Nmem @ W_mu)
#define WS_PNV   17235968ULL   // f32 [64][512]  (Nmem @ W_var)
#define WS_MEMT  17367040ULL   // f32 [512][128] (memT[d][k], k<64:Amem else Nmem)
#define WS_TATT  17629184ULL   // f32 [3][32768] (0=A_att,1=N_att,2=N_Aatt)
#define WS_IDX   18022400ULL   // int [3][64][40]
#define WS_GATH  18053120ULL   // f32 [3][64][512]
#define WS_NORM  18446336ULL   // f32 [128]
#define WS_KL    18446848ULL   // f32 accumulator
#define WS_TRIPB 18447360ULL   // f32 [64]
#define WS_SUM   18447616ULL   // f32 [64][512] anchor partial sums

__device__ __forceinline__ u16 f2bf(float f) {
    union { float f; unsigned int u; } c; c.f = f;
    unsigned int r = c.u + 0x7fffu + ((c.u >> 16) & 1u);
    return (u16)(r >> 16);
}
__device__ __forceinline__ float bf2f(u16 h) {
    union { unsigned int u; float f; } c; c.u = ((unsigned int)h) << 16;
    return c.f;
}

__device__ __forceinline__ float blk_sum(float v, float* red) {
    #pragma unroll
    for (int o = 32; o; o >>= 1) v += __shfl_xor(v, o);
    int tid = threadIdx.x;
    if ((tid & 63) == 0) red[tid >> 6] = v;
    __syncthreads();
    float r = red[0] + red[1] + red[2] + red[3];
    __syncthreads();
    return r;
}

// stage a 128x32 bf16 tile into LDS linearly -- 512-thread version (one 16B load each)
__device__ __forceinline__ void stage32_512(const u16* __restrict__ g, int row0, int ld, int k0,
                                            u16* s, int tid) {
    const u16* src = g + (size_t)(row0 + (tid >> 2)) * ld + k0 + (tid & 3) * 8;
    __builtin_amdgcn_global_load_lds((const __attribute__((address_space(1))) void*)src,
                                     (__attribute__((address_space(3))) void*)(s + tid * 8),
                                     16, 0, 0);
}

// ---------------- prep: memT transpose + zero KL/SUM ----------------
__global__ __launch_bounds__(256) void k_prep(const float* __restrict__ Amem, const float* __restrict__ Nmem,
                                              char* __restrict__ ws) {
    int i = blockIdx.x * 256 + threadIdx.x;
    if (i == 0) *(float*)(ws + WS_KL) = 0.f;
    if (i < 32768) ((float*)(ws + WS_SUM))[i] = 0.f;
    int d = i >> 7, k = i & 127;
    float v = (k < 64) ? Amem[(size_t)k * 512 + d] : Nmem[(size_t)(k - 64) * 512 + d];
    ((float*)(ws + WS_MEMT))[i] = v;
}

// ---------------- proj: P = mem @ W, f32 [k][n] + bf16 transposed ----------------
__global__ __launch_bounds__(256) void k_proj(const float* __restrict__ Amem, const float* __restrict__ Nmem,
                                              const float* __restrict__ Wmu, const float* __restrict__ Wvar,
                                              float* __restrict__ pam, float* __restrict__ pnm,
                                              float* __restrict__ pnv, u16* __restrict__ bct,
                                              u16* __restrict__ pvt) {
    __shared__ float mr[512];
    int mat = blockIdx.x >> 6, k = blockIdx.x & 63, tid = threadIdx.x;
    const float* mrow = ((mat == 0) ? Amem : Nmem) + (size_t)k * 512;
    const float* W = (mat == 2) ? Wvar : Wmu;
    mr[tid] = mrow[tid]; mr[tid + 256] = mrow[tid + 256];
    __syncthreads();
    float s0 = 0.f, s1 = 0.f;
    for (int d = 0; d < 512; ++d) {
        float m = mr[d];
        s0 += m * W[(size_t)d * 512 + tid];
        s1 += m * W[(size_t)d * 512 + tid + 256];
    }
    if (mat == 0) {
        pam[(size_t)k * 512 + tid] = s0; pam[(size_t)k * 512 + tid + 256] = s1;
        bct[(size_t)tid * 128 + k] = f2bf(s0); bct[(size_t)(tid + 256) * 128 + k] = f2bf(s1);
    } else if (mat == 1) {
        pnm[(size_t)k * 512 + tid] = s0; pnm[(size_t)k * 512 + tid + 256] = s1;
        bct[(size_t)tid * 128 + 64 + k] = f2bf(s0); bct[(size_t)(tid + 256) * 128 + 64 + k] = f2bf(s1);
    } else {
        pnv[(size_t)k * 512 + tid] = s0; pnv[(size_t)k * 512 + tid + 256] = s1;
        pvt[(size_t)tid * 64 + k] = f2bf(s0); pvt[(size_t)(tid + 256) * 64 + k] = f2bf(s1);
    }
}

// ---------------- dots: att bf16, sigmoid, t_att, x->F_M left (f32 copy) ----------------
// LDS-conflict-free layout: xt[d][row] transposed x, memT split msL/msH at 16B grain.
__global__ __launch_bounds__(256) void k_dots(const float* __restrict__ x, char* __restrict__ ws,
                                              float* __restrict__ out) {
    __shared__ float xt[64][68];
    __shared__ float msbuf[2][64][64];
    float (*msL)[64] = msbuf[0];
    float (*msH)[64] = msbuf[1];
    float (*attl)[128] = (float(*)[128])&msbuf[0][0][0];

    int tid = threadIdx.x;
    int row0 = blockIdx.x * 64;
    const float* memT = (const float*)(ws + WS_MEMT);
    u16* attb = (u16*)(ws + WS_ATTB);
    int ty = tid >> 4, tx = tid & 15;

    float acc[4][8];
    #pragma unroll
    for (int r = 0; r < 4; ++r)
        #pragma unroll
        for (int j = 0; j < 8; ++j) acc[r][j] = 0.f;

    for (int dc = 0; dc < 8; ++dc) {
        int d0 = dc * 64;
        {   // x tile: 4x4 f32x4 block per thread -> F_M left (f32 copy) + transposed LDS
            const float* sp = x + (size_t)(row0 + ty * 4) * 512 + d0 + tx * 4;
            float* op = out + (size_t)(row0 + ty * 4) * 1024 + d0 + tx * 4;
            f32x4 a0 = *(const f32x4*)(sp);
            f32x4 a1 = *(const f32x4*)(sp + 512);
            f32x4 a2 = *(const f32x4*)(sp + 1024);
            f32x4 a3 = *(const f32x4*)(sp + 1536);
            *(f32x4*)(op) = a0; *(f32x4*)(op + 1024) = a1;
            *(f32x4*)(op + 2048) = a2; *(f32x4*)(op + 3072) = a3;
            *(f32x4*)&xt[tx * 4 + 0][ty * 4] = (f32x4){a0.x, a1.x, a2.x, a3.x};
            *(f32x4*)&xt[tx * 4 + 1][ty * 4] = (f32x4){a0.y, a1.y, a2.y, a3.y};
            *(f32x4*)&xt[tx * 4 + 2][ty * 4] = (f32x4){a0.z, a1.z, a2.z, a3.z};
            *(f32x4*)&xt[tx * 4 + 3][ty * 4] = (f32x4){a0.w, a1.w, a2.w, a3.w};
        }
        {   // memT chunk -> msL/msH (16B-granular split)
            const f32x4* mw = (const f32x4*)(memT + (size_t)d0 * 128);
            #pragma unroll
            for (int j = 0; j < 8; ++j) {
                int w = tid + j * 256;
                f32x4 v = mw[w];
                int d = w >> 5, cw = w & 31;
                float* dst = (cw & 1) ? &msH[d][(cw >> 1) * 4] : &msL[d][(cw >> 1) * 4];
                *(f32x4*)dst = v;
            }
        }
        __syncthreads();
        #pragma unroll 2
        for (int d = 0; d < 64; ++d) {
            f32x4 xv  = *(const f32x4*)&xt[d][ty * 4];
            f32x4 mlo = *(const f32x4*)&msL[d][tx * 4];
            f32x4 mhi = *(const f32x4*)&msH[d][tx * 4];
            #pragma unroll
            for (int r = 0; r < 4; ++r) {
                acc[r][0] += xv[r] * mlo.x; acc[r][1] += xv[r] * mlo.y;
                acc[r][2] += xv[r] * mlo.z; acc[r][3] += xv[r] * mlo.w;
                acc[r][4] += xv[r] * mhi.x; acc[r][5] += xv[r] * mhi.y;
                acc[r][6] += xv[r] * mhi.z; acc[r][7] += xv[r] * mhi.w;
            }
        }
        __syncthreads();
    }

    // sigmoid -> att bf16 (ws) + f32 LDS (attl overlays msbuf) for t_att
    #pragma unroll
    for (int r = 0; r < 4; ++r) {
        u16* bp = attb + (size_t)(row0 + ty * 4 + r) * 128 + tx * 8;
        #pragma unroll
        for (int j = 0; j < 8; ++j) {
            float logit = acc[r][j] * 0.044194173824159216f;  // 1/sqrt(512)
            float av = 1.f / (1.f + expf(-logit));
            attl[ty * 4 + r][tx * 8 + j] = av;
            bp[j] = f2bf(av);
        }
    }
    __syncthreads();

    // t_att: top-5-of-64 via reduce-max + ballot knockout
    int lane = tid & 63, w = tid >> 6;
    float* tatt = (float*)(ws + WS_TATT);
    int half = row0 >> 15;
    for (int rr = 0; rr < 16; ++rr) {
        int r = w * 16 + rr;
        int lr = (row0 + r) & 32767;
        #pragma unroll
        for (int side = 0; side < 2; ++side) {
            float cur = attl[r][side * 64 + lane];
            float sum5 = 0.f;
            #pragma unroll
            for (int it = 0; it < 5; ++it) {
                float m = cur;
                #pragma unroll
                for (int o = 32; o; o >>= 1) { float t = __shfl_xor(m, o); m = fmaxf(m, t); }
                sum5 += m;
                unsigned long long bl = __ballot(cur == m);
                int srcl = __ffsll(bl) - 1;
                if (lane == srcl) cur = -INFINITY;
            }
            if (lane == 0) {
                float tv = sum5 / 5.f;
                if (half) {
                    if (side == 0) { out[O_AATT + lr]  = tv; tatt[lr] = tv; }
                    else           { out[O_NAATT + lr] = tv; tatt[2 * 32768 + lr] = tv; }
                } else {
                    if (side == 0) { out[O_ANATT + lr] = tv; }
                    else           { out[O_NATT + lr]  = tv; tatt[32768 + lr] = tv; }
                }
            }
        }
    }
}

// ---------------- top-33: single-pass rank (== stable top_k, lower index wins ties) ----
__global__ __launch_bounds__(256) void k_topk(const float* __restrict__ tatt, int* __restrict__ idx) {
    __shared__ float vals[512];
    int s = blockIdx.x >> 6, b = blockIdx.x & 63, tid = threadIdx.x;
    const float* src = tatt + (size_t)s * 32768 + b * 512;
    vals[tid] = src[tid]; vals[tid + 256] = src[tid + 256];
    __syncthreads();
    #pragma unroll
    for (int e = 0; e < 2; ++e) {
        int i = tid + e * 256;
        float v = vals[i];
        int rank = 0;
        for (int j = 0; j < 512; j += 4) {
            f32x4 w4 = *(const f32x4*)&vals[j];
            rank += (w4.x > v) || (w4.x == v && (j + 0) < i);
            rank += (w4.y > v) || (w4.y == v && (j + 1) < i);
            rank += (w4.z > v) || (w4.z == v && (j + 2) < i);
            rank += (w4.w > v) || (w4.w == v && (j + 3) < i);
        }
        if (rank < 33) idx[(s * 64 + b) * 40 + rank] = i;
    }
}

// ---------------- gather means of x (192 blocks: one per s,b) ----------------
__global__ __launch_bounds__(256) void k_gather3(const float* __restrict__ x, const int* __restrict__ idx,
                                                 float* __restrict__ gath) {
    __shared__ int il[33];
    int s = blockIdx.x >> 6, b = blockIdx.x & 63, tid = threadIdx.x;
    if (tid < 33) il[tid] = idx[(s * 64 + b) * 40 + tid];
    __syncthreads();
    int srcb = (s == 1) ? b : 64 + b;
    const float* xb = x + (size_t)srcb * 262144;
    int d0 = tid * 2;
    float a0 = 0.f, a1 = 0.f;
    for (int i = 0; i < 33; ++i) {
        const float* p = xb + (size_t)il[i] * 512 + d0;
        a0 += p[0]; a1 += p[1];
    }
    gath[((size_t)s * 64 + b) * 512 + d0]     = a0 / 33.f;
    gath[((size_t)s * 64 + b) * 512 + d0 + 1] = a1 / 33.f;
}

// ---------------- triplet per-b (64 blocks) ----------------
__global__ __launch_bounds__(256) void k_triplet(const float* __restrict__ gath, float* __restrict__ tripb) {
    __shared__ float red[8];
    int b = blockIdx.x, tid = threadIdx.x;
    const float* a = gath + (size_t)(64 + b) * 512;
    const float* p = gath + (size_t)(128 + b) * 512;
    const float* n = gath + (size_t)(b) * 512;
    float a0 = a[tid], a1 = a[tid + 256];
    float p0 = p[tid], p1 = p[tid + 256];
    float n0 = n[tid], n1 = n[tid + 256];
    float na  = sqrtf(blk_sum(a0 * a0 + a1 * a1, red));
    float npv = sqrtf(blk_sum(p0 * p0 + p1 * p1, red));
    float nn  = sqrtf(blk_sum(n0 * n0 + n1 * n1, red));
    float e0 = a0 / na - p0 / npv + 1e-6f, e1 = a1 / na - p1 / npv + 1e-6f;
    float f0 = a0 / na - n0 / nn  + 1e-6f, f1 = a1 / na - n1 / nn  + 1e-6f;
    float dap = sqrtf(blk_sum(e0 * e0 + e1 * e1, red));
    float dan = sqrtf(blk_sum(f0 * f0 + f1 * f1, red));
    if (tid == 0) tripb[b] = fmaxf(dap - dan + 1.f, 0.f);
}

// ---------------- G1: N-half right F_M via MFMA (3 GEMMs K=64) + kl. 512 threads ----------------
__global__ __launch_bounds__(512) void kG1(const u16* __restrict__ attb, const u16* __restrict__ bct,
                                           const u16* __restrict__ pvt, const float* __restrict__ bmu,
                                           const float* __restrict__ bvar, const float* __restrict__ epsv,
                                           float* __restrict__ fm, float* __restrict__ klacc) {
    __shared__ u16 sAA[128 * 32];
    __shared__ u16 sAN[128 * 32];
    __shared__ u16 sBA[128 * 32];
    __shared__ u16 sBN[128 * 32];
    __shared__ u16 sBV[128 * 32];
    __shared__ float red[8];
    int tid = threadIdx.x, lane = tid & 63, wid = tid >> 6;
    int wr = wid >> 2, wc = wid & 3;            // 8 waves: 2 x 4; wave tile 64 rows x 32 cols
    int cl = lane & 15, rq = lane >> 4;
    int m0 = blockIdx.x * 128, c0 = blockIdx.y * 128;

    f32x4 aA[4][2], aN[4][2], aV[4][2];
    #pragma unroll
    for (int i = 0; i < 4; ++i)
        #pragma unroll
        for (int j = 0; j < 2; ++j) { aA[i][j] = (f32x4)0.f; aN[i][j] = (f32x4)0.f; aV[i][j] = (f32x4)0.f; }

    for (int kt = 0; kt < 2; ++kt) {
        stage32_512(attb, m0, 128, kt * 32, sAA, tid);
        stage32_512(attb, m0, 128, 64 + kt * 32, sAN, tid);
        stage32_512(bct, c0, 128, kt * 32, sBA, tid);
        stage32_512(bct, c0, 128, 64 + kt * 32, sBN, tid);
        stage32_512(pvt, c0, 64, kt * 32, sBV, tid);
        __syncthreads();
        s16x8 fA[4], fN[4], bA[2], bN[2], bV[2];
        #pragma unroll
        for (int i = 0; i < 4; ++i) {
            fA[i] = *(const s16x8*)&sAA[(wr * 64 + i * 16 + cl) * 32 + rq * 8];
            fN[i] = *(const s16x8*)&sAN[(wr * 64 + i * 16 + cl) * 32 + rq * 8];
        }
        #pragma unroll
        for (int n = 0; n < 2; ++n) {
            bA[n] = *(const s16x8*)&sBA[(wc * 32 + n * 16 + cl) * 32 + rq * 8];
            bN[n] = *(const s16x8*)&sBN[(wc * 32 + n * 16 + cl) * 32 + rq * 8];
            bV[n] = *(const s16x8*)&sBV[(wc * 32 + n * 16 + cl) * 32 + rq * 8];
        }
        #pragma unroll
        for (int mi = 0; mi < 4; ++mi)
            #pragma unroll
            for (int ni = 0; ni < 2; ++ni) {
                aA[mi][ni] = __builtin_amdgcn_mfma_f32_16x16x32_bf16(fA[mi], bA[ni], aA[mi][ni], 0, 0, 0);
                aN[mi][ni] = __builtin_amdgcn_mfma_f32_16x16x32_bf16(fN[mi], bN[ni], aN[mi][ni], 0, 0, 0);
                aV[mi][ni] = __builtin_amdgcn_mfma_f32_16x16x32_bf16(fN[mi], bV[ni], aV[mi][ni], 0, 0, 0);
            }
        __syncthreads();
    }

    float kll = 0.f;
    #pragma unroll
    for (int mi = 0; mi < 4; ++mi)
        #pragma unroll
        for (int ni = 0; ni < 2; ++ni) {
            int col = c0 + wc * 32 + ni * 16 + cl;
            int rowb = m0 + wr * 64 + mi * 16 + rq * 4;
            float bm = bmu[col], bv = bvar[col];
            #pragma unroll
            for (int q = 0; q < 4; ++q) {
                int row = rowb + q;
                float muN = aN[mi][ni][q] + bm;
                float var = aV[mi][ni][q] + bv;
                float ev = expf(var);
                float muA = aA[mi][ni][q] + bm;
                fm[(size_t)row * 1024 + 512 + col] =
                    muN + epsv[(size_t)row * 512 + col] * sqrtf(ev) + muA;
                kll += 1.f + var - muN * muN - ev;
            }
        }
    #pragma unroll
    for (int o = 32; o; o >>= 1) kll += __shfl_xor(kll, o);
    if (lane == 0) red[wid] = kll;
    __syncthreads();
    if (tid == 0) {
        float s = 0.f;
        #pragma unroll
        for (int i = 0; i < 8; ++i) s += red[i];
        atomicAdd(klacc, s);
    }
}

// ---------------- G3: A-half right F_M via MFMA (K=128). 512 threads ----------------
__global__ __launch_bounds__(512) void kG3(const u16* __restrict__ attb, const u16* __restrict__ bct,
                                           const float* __restrict__ bmu, float* __restrict__ fm) {
    __shared__ u16 sA[128 * 32];
    __shared__ u16 sB[128 * 32];
    int tid = threadIdx.x, lane = tid & 63, wid = tid >> 6;
    int wr = wid >> 2, wc = wid & 3;
    int cl = lane & 15, rq = lane >> 4;
    int m0 = blockIdx.x * 128, c0 = blockIdx.y * 128;

    f32x4 acc[4][2];
    #pragma unroll
    for (int i = 0; i < 4; ++i)
        #pragma unroll
        for (int j = 0; j < 2; ++j) acc[i][j] = (f32x4)0.f;

    for (int kt = 0; kt < 4; ++kt) {
        stage32_512(attb, 32768 + m0, 128, kt * 32, sA, tid);
        stage32_512(bct, c0, 128, kt * 32, sB, tid);
        __syncthreads();
        s16x8 fa[4], fb[2];
        #pragma unroll
        for (int i = 0; i < 4; ++i)
            fa[i] = *(const s16x8*)&sA[(wr * 64 + i * 16 + cl) * 32 + rq * 8];
        #pragma unroll
        for (int n = 0; n < 2; ++n)
            fb[n] = *(const s16x8*)&sB[(wc * 32 + n * 16 + cl) * 32 + rq * 8];
        #pragma unroll
        for (int mi = 0; mi < 4; ++mi)
            #pragma unroll
            for (int ni = 0; ni < 2; ++ni)
                acc[mi][ni] = __builtin_amdgcn_mfma_f32_16x16x32_bf16(fa[mi], fb[ni], acc[mi][ni], 0, 0, 0);
        __syncthreads();
    }
    #pragma unroll
    for (int mi = 0; mi < 4; ++mi)
        #pragma unroll
        for (int ni = 0; ni < 2; ++ni) {
            int col = c0 + wc * 32 + ni * 16 + cl;
            int rowb = 32768 + m0 + wr * 64 + mi * 16 + rq * 4;
            float bm2 = 2.f * bmu[col];
            #pragma unroll
            for (int q = 0; q < 4; ++q)
                fm[(size_t)(rowb + q) * 1024 + 512 + col] = acc[mi][ni][q] + bm2;
        }
}

// ---------------- anchor partial sums (192 blocks: b x 3 segs of 11 rows) ----------------
__global__ __launch_bounds__(256) void k_gather2a(const int* __restrict__ idx, const u16* __restrict__ attb,
                                                  const float* __restrict__ pnm, const float* __restrict__ pnv,
                                                  const float* __restrict__ bmu, const float* __restrict__ bvar,
                                                  const float* __restrict__ epsv, float* __restrict__ SUM) {
    __shared__ float arow[64];
    int blk = blockIdx.x, b = blk / 3, seg = blk % 3;
    int tid = threadIdx.x;
    float s0 = 0.f, s1 = 0.f;
    for (int i = seg * 11; i < seg * 11 + 11; ++i) {
        int t = idx[(64 + b) * 40 + i];   // N_idx
        size_t r = (size_t)b * 512 + t;
        __syncthreads();
        if (tid < 64) arow[tid] = bf2f(attb[r * 128 + 64 + tid]);
        __syncthreads();
        float mu0 = bmu[tid], mu1 = bmu[tid + 256];
        float v0 = bvar[tid], v1 = bvar[tid + 256];
        for (int k = 0; k < 64; ++k) {
            float a = arow[k];
            mu0 += a * pnm[(size_t)k * 512 + tid];
            mu1 += a * pnm[(size_t)k * 512 + tid + 256];
            v0  += a * pnv[(size_t)k * 512 + tid];
            v1  += a * pnv[(size_t)k * 512 + tid + 256];
        }
        s0 += mu0 + epsv[r * 512 + tid]       * sqrtf(expf(v0));
        s1 += mu1 + epsv[r * 512 + tid + 256] * sqrtf(expf(v1));
    }
    atomicAdd(&SUM[(size_t)b * 512 + tid], s0);
    atomicAdd(&SUM[(size_t)b * 512 + tid + 256], s1);
}

// ---------------- anchor norms from SUM ----------------
__global__ __launch_bounds__(256) void k_norm2a(const float* __restrict__ SUM, float* __restrict__ norms) {
    __shared__ float red[8];
    int b = blockIdx.x, tid = threadIdx.x;
    float s0 = SUM[(size_t)b * 512 + tid] / 33.f;
    float s1 = SUM[(size_t)b * 512 + tid + 256] / 33.f;
    float ss = blk_sum(s0 * s0 + s1 * s1, red);
    if (tid == 0) norms[b] = sqrtf(ss);
}

// ---------------- negative norms: mean-att @ P_A_mu + b_mu (linearity) ----------------
__global__ __launch_bounds__(256) void k_gather2b(const int* __restrict__ idx, const u16* __restrict__ attb,
                                                  const float* __restrict__ pam, const float* __restrict__ bmu,
                                                  float* __restrict__ norms) {
    __shared__ float meanA[64];
    __shared__ float red[8];
    int b = blockIdx.x, tid = threadIdx.x;
    if (tid < 64) {
        float s = 0.f;
        for (int i = 0; i < 33; ++i) {
            int t = idx[b * 40 + i];      // A_idx
            s += bf2f(attb[(size_t)(32768 + b * 512 + t) * 128 + tid]);
        }
        meanA[tid] = s * (1.f / 33.f);
    }
    __syncthreads();
    float s0 = bmu[tid], s1 = bmu[tid + 256];
    #pragma unroll 4
    for (int k = 0; k < 64; ++k) {
        float m = meanA[k];
        s0 += m * pam[(size_t)k * 512 + tid];
        s1 += m * pam[(size_t)k * 512 + tid + 256];
    }
    float ss = blk_sum(s0 * s0 + s1 * s1, red);
    if (tid == 0) norms[64 + b] = sqrtf(ss);
}

// ---------------- finalize: triplet + distance + kl ----------------
__global__ __launch_bounds__(64) void k_final(const float* __restrict__ norms, const float* __restrict__ klacc,
                                              const float* __restrict__ tripb, float* __restrict__ out) {
    int tid = threadIdx.x;
    float v = fmaxf(100.f - norms[64 + tid] + norms[tid], 0.f);
    float t = tripb[tid];
    #pragma unroll
    for (int o = 32; o; o >>= 1) { v += __shfl_xor(v, o); t += __shfl_xor(t, o); }
    if (tid == 0) {
        out[O_DIST] = v / 64.f;
        out[O_TRIP] = t / 64.f;
        out[O_KL]   = -0.5f * (*klacc) / 32768.f;
    }
}

extern "C" void kernel_launch(void* const* d_in, const int* in_sizes, int n_in,
                              void* d_out, int out_size, void* d_ws, size_t ws_size,
                              hipStream_t stream) {
    const float* x    = (const float*)d_in[0];
    const float* Amem = (const float*)d_in[1];
    const float* Nmem = (const float*)d_in[2];
    const float* Wmu  = (const float*)d_in[3];
    const float* bmu  = (const float*)d_in[4];
    const float* Wvar = (const float*)d_in[5];
    const float* bvar = (const float*)d_in[6];
    const float* eps  = (const float*)d_in[7];
    float* out = (float*)d_out;
    char* ws = (char*)d_ws;
    const u16* attb  = (const u16*)(ws + WS_ATTB);
    const u16* bct   = (const u16*)(ws + WS_BCT);
    const u16* pvt   = (const u16*)(ws + WS_PVT);
    const float* pam = (const float*)(ws + WS_PAM);
    const float* pnm = (const float*)(ws + WS_PNM);
    const float* pnv = (const float*)(ws + WS_PNV);
    const int* idx   = (const int*)(ws + WS_IDX);

    k_prep<<<256, 256, 0, stream>>>(Amem, Nmem, ws);
    k_proj<<<192, 256, 0, stream>>>(Amem, Nmem, Wmu, Wvar,
                                    (float*)(ws + WS_PAM), (float*)(ws + WS_PNM), (float*)(ws + WS_PNV),
                                    (u16*)(ws + WS_BCT), (u16*)(ws + WS_PVT));
    k_dots<<<1024, 256, 0, stream>>>(x, ws, out);
    k_topk<<<192, 256, 0, stream>>>((const float*)(ws + WS_TATT), (int*)(ws + WS_IDX));
    k_gather3<<<192, 256, 0, stream>>>(x, idx, (float*)(ws + WS_GATH));
    k_triplet<<<64, 256, 0, stream>>>((const float*)(ws + WS_GATH), (float*)(ws + WS_TRIPB));
    kG1<<<dim3(256, 4), 512, 0, stream>>>(attb, bct, pvt, bmu, bvar, eps, out, (float*)(ws + WS_KL));
    kG3<<<dim3(256, 4), 512, 0, stream>>>(attb, bct, bmu, out);
    k_gather2a<<<192, 256, 0, stream>>>(idx, attb, pnm, pnv, bmu, bvar, eps, (float*)(ws + WS_SUM));
    k_norm2a<<<64, 256, 0, stream>>>((const float*)(ws + WS_SUM), (float*)(ws + WS_NORM));
    k_gather2b<<<64, 256, 0, stream>>>(idx, attb, pam, bmu, (float*)(ws + WS_NORM));
    k_final<<<1, 64, 0, stream>>>((const float*)(ws + WS_NORM), (const float*)(ws + WS_KL),
                                  (const float*)(ws + WS_TRIPB), out);
}

// Round 11
// 346.594 us; speedup vs baseline: 2.0658x; 1.1733x over previous
//
#include <hip/hip_runtime.h>
#include <hip/hip_bf16.h>
#include <math.h>

// B=128, T=512, D=512, K=64; mid=64; rows per half = 32768. f32 in/out.
typedef unsigned short u16;
typedef __attribute__((ext_vector_type(4))) float f32x4;
typedef __attribute__((ext_vector_type(8))) short s16x8;

// ---------------- output offsets (f32 elements) ----------------
#define O_FM    0ULL
#define O_TRIP  67108864ULL
#define O_KL    67108865ULL
#define O_DIST  67108866ULL
#define O_AATT  67108867ULL
#define O_NATT  67141635ULL
#define O_ANATT 67174403ULL
#define O_NAATT 67207171ULL

// ---------------- ws offsets (bytes), total ~18.6 MB (<= 35 MB proven safe) ----
#define WS_ATTB  0ULL          // att bf16 [65536][128] (k<64: vs Amem, k>=64: vs Nmem)
#define WS_BCT   16777216ULL   // bf16 [512 n][128 k]: k<64 = pam^T, k>=64 = pnm^T
#define WS_PVT   16908288ULL   // bf16 [512 n][64 k] = pnv^T
#define WS_PAM   16973824ULL   // f32 [64][512]  (Amem @ W_mu)
#define WS_PNM   17104896ULL   // f32 [64][512]  (Nmem @ W_mu)
#define WS_PNV   17235968ULL   // f32 [64][512]  (Nmem @ W_var)
#define WS_MEMT  17367040ULL   // f32 [512][128] (memT[d][k], k<64:Amem else Nmem)
#define WS_TATT  17629184ULL   // f32 [3][32768] (0=A_att,1=N_att,2=N_Aatt)
#define WS_IDX   18022400ULL   // int [3][64][40]
#define WS_GATH  18053120ULL   // f32 [3][64][512]
#define WS_NORM  18446336ULL   // f32 [128]
#define WS_KL    18446848ULL   // f32 accumulator
#define WS_TRIPB 18447360ULL   // f32 [64]
#define WS_SUM   18447616ULL   // f32 [64][512] anchor partial sums

__device__ __forceinline__ u16 f2bf(float f) {
    union { float f; unsigned int u; } c; c.f = f;
    unsigned int r = c.u + 0x7fffu + ((c.u >> 16) & 1u);
    return (u16)(r >> 16);
}
__device__ __forceinline__ float bf2f(u16 h) {
    union { unsigned int u; float f; } c; c.u = ((unsigned int)h) << 16;
    return c.f;
}

__device__ __forceinline__ float blk_sum(float v, float* red) {
    #pragma unroll
    for (int o = 32; o; o >>= 1) v += __shfl_xor(v, o);
    int tid = threadIdx.x;
    if ((tid & 63) == 0) red[tid >> 6] = v;
    __syncthreads();
    float r = red[0] + red[1] + red[2] + red[3];
    __syncthreads();
    return r;
}

// stage a 128x32 bf16 tile into LDS linearly -- 512-thread version (one 16B load each)
__device__ __forceinline__ void stage32_512(const u16* __restrict__ g, int row0, int ld, int k0,
                                            u16* s, int tid) {
    const u16* src = g + (size_t)(row0 + (tid >> 2)) * ld + k0 + (tid & 3) * 8;
    __builtin_amdgcn_global_load_lds((const __attribute__((address_space(1))) void*)src,
                                     (__attribute__((address_space(3))) void*)(s + tid * 8),
                                     16, 0, 0);
}

// ---------------- prep: memT transpose + zero KL/SUM ----------------
__global__ __launch_bounds__(256) void k_prep(const float* __restrict__ Amem, const float* __restrict__ Nmem,
                                              char* __restrict__ ws) {
    int i = blockIdx.x * 256 + threadIdx.x;
    if (i == 0) *(float*)(ws + WS_KL) = 0.f;
    if (i < 32768) ((float*)(ws + WS_SUM))[i] = 0.f;
    int d = i >> 7, k = i & 127;
    float v = (k < 64) ? Amem[(size_t)k * 512 + d] : Nmem[(size_t)(k - 64) * 512 + d];
    ((float*)(ws + WS_MEMT))[i] = v;
}

// ---------------- proj: P = mem @ W, f32 [k][n] + bf16 transposed ----------------
__global__ __launch_bounds__(256) void k_proj(const float* __restrict__ Amem, const float* __restrict__ Nmem,
                                              const float* __restrict__ Wmu, const float* __restrict__ Wvar,
                                              float* __restrict__ pam, float* __restrict__ pnm,
                                              float* __restrict__ pnv, u16* __restrict__ bct,
                                              u16* __restrict__ pvt) {
    __shared__ float mr[512];
    int mat = blockIdx.x >> 6, k = blockIdx.x & 63, tid = threadIdx.x;
    const float* mrow = ((mat == 0) ? Amem : Nmem) + (size_t)k * 512;
    const float* W = (mat == 2) ? Wvar : Wmu;
    mr[tid] = mrow[tid]; mr[tid + 256] = mrow[tid + 256];
    __syncthreads();
    float s0 = 0.f, s1 = 0.f;
    for (int d = 0; d < 512; ++d) {
        float m = mr[d];
        s0 += m * W[(size_t)d * 512 + tid];
        s1 += m * W[(size_t)d * 512 + tid + 256];
    }
    if (mat == 0) {
        pam[(size_t)k * 512 + tid] = s0; pam[(size_t)k * 512 + tid + 256] = s1;
        bct[(size_t)tid * 128 + k] = f2bf(s0); bct[(size_t)(tid + 256) * 128 + k] = f2bf(s1);
    } else if (mat == 1) {
        pnm[(size_t)k * 512 + tid] = s0; pnm[(size_t)k * 512 + tid + 256] = s1;
        bct[(size_t)tid * 128 + 64 + k] = f2bf(s0); bct[(size_t)(tid + 256) * 128 + 64 + k] = f2bf(s1);
    } else {
        pnv[(size_t)k * 512 + tid] = s0; pnv[(size_t)k * 512 + tid + 256] = s1;
        pvt[(size_t)tid * 64 + k] = f2bf(s0); pvt[(size_t)(tid + 256) * 64 + k] = f2bf(s1);
    }
}

// ---------------- dots: att bf16, sigmoid, in-register t_att, x->F_M left (f32 copy) ----
// LDS = xs[64][34] (8.5 KB) + msL/msH[32][64] (16 KB) = 24.5 KB -> ~6 blocks/CU.
__global__ __launch_bounds__(256) void k_dots(const float* __restrict__ x, char* __restrict__ ws,
                                              float* __restrict__ out) {
    __shared__ float xs[64][34];
    __shared__ float msL[32][64];
    __shared__ float msH[32][64];

    int tid = threadIdx.x;
    int row0 = blockIdx.x * 64;
    const float* memT = (const float*)(ws + WS_MEMT);
    u16* attb = (u16*)(ws + WS_ATTB);
    int ty = tid >> 4, tx = tid & 15;

    float acc[4][8];
    #pragma unroll
    for (int r = 0; r < 4; ++r)
        #pragma unroll
        for (int j = 0; j < 8; ++j) acc[r][j] = 0.f;

    for (int dc = 0; dc < 16; ++dc) {
        int d0 = dc * 32;
        {   // stage x chunk [64 rows][32 d] + exact f32 copy into F_M left half
            int rr = tid >> 2, q = tid & 3;
            const float* src = x + (size_t)(row0 + rr) * 512 + d0 + q * 8;
            float* dst = out + (size_t)(row0 + rr) * 1024 + d0 + q * 8;
            f32x4 v0 = *(const f32x4*)(src);
            f32x4 v1 = *(const f32x4*)(src + 4);
            *(f32x4*)(dst) = v0;
            *(f32x4*)(dst + 4) = v1;
            *(f32x4*)&xs[rr][q * 8]     = v0;
            *(f32x4*)&xs[rr][q * 8 + 4] = v1;
        }
        {   // stage memT chunk [32 d][128] -> msL/msH (16B-granular split)
            const f32x4* mw = (const f32x4*)(memT + (size_t)d0 * 128);
            #pragma unroll
            for (int j = 0; j < 4; ++j) {
                int w = tid + j * 256;
                f32x4 v = mw[w];
                int d = w >> 5, cw = w & 31;
                float* dst = (cw & 1) ? &msH[d][(cw >> 1) * 4] : &msL[d][(cw >> 1) * 4];
                *(f32x4*)dst = v;
            }
        }
        __syncthreads();
        #pragma unroll 2
        for (int d = 0; d < 32; ++d) {
            f32x4 mlo = *(const f32x4*)&msL[d][tx * 4];
            f32x4 mhi = *(const f32x4*)&msH[d][tx * 4];
            float x0 = xs[ty * 4 + 0][d];
            float x1 = xs[ty * 4 + 1][d];
            float x2 = xs[ty * 4 + 2][d];
            float x3 = xs[ty * 4 + 3][d];
            acc[0][0] += x0 * mlo.x; acc[0][1] += x0 * mlo.y; acc[0][2] += x0 * mlo.z; acc[0][3] += x0 * mlo.w;
            acc[0][4] += x0 * mhi.x; acc[0][5] += x0 * mhi.y; acc[0][6] += x0 * mhi.z; acc[0][7] += x0 * mhi.w;
            acc[1][0] += x1 * mlo.x; acc[1][1] += x1 * mlo.y; acc[1][2] += x1 * mlo.z; acc[1][3] += x1 * mlo.w;
            acc[1][4] += x1 * mhi.x; acc[1][5] += x1 * mhi.y; acc[1][6] += x1 * mhi.z; acc[1][7] += x1 * mhi.w;
            acc[2][0] += x2 * mlo.x; acc[2][1] += x2 * mlo.y; acc[2][2] += x2 * mlo.z; acc[2][3] += x2 * mlo.w;
            acc[2][4] += x2 * mhi.x; acc[2][5] += x2 * mhi.y; acc[2][6] += x2 * mhi.z; acc[2][7] += x2 * mhi.w;
            acc[3][0] += x3 * mlo.x; acc[3][1] += x3 * mlo.y; acc[3][2] += x3 * mlo.z; acc[3][3] += x3 * mlo.w;
            acc[3][4] += x3 * mhi.x; acc[3][5] += x3 * mhi.y; acc[3][6] += x3 * mhi.z; acc[3][7] += x3 * mhi.w;
        }
        __syncthreads();
    }

    // sigmoid in place -> att bf16 to ws
    #pragma unroll
    for (int r = 0; r < 4; ++r) {
        u16* bp = attb + (size_t)(row0 + ty * 4 + r) * 128 + tx * 8;
        #pragma unroll
        for (int j = 0; j < 8; ++j) {
            float logit = acc[r][j] * 0.044194173824159216f;  // 1/sqrt(512)
            float av = 1.f / (1.f + expf(-logit));
            acc[r][j] = av;
            bp[j] = f2bf(av);
        }
    }

    // t_att: in-register top-5-of-64 per (row, side); lanes tx0-7 = side0, tx8-15 = side1
    int lane = tid & 63;
    int side = tx >> 3;
    unsigned long long gmask = 0xFFull << (lane & 56);
    float* tatt = (float*)(ws + WS_TATT);
    int half = row0 >> 15;
    #pragma unroll
    for (int rr = 0; rr < 4; ++rr) {
        float v[8];
        #pragma unroll
        for (int j = 0; j < 8; ++j) v[j] = acc[rr][j];
        float sum5 = 0.f;
        #pragma unroll
        for (int it = 0; it < 5; ++it) {
            float m = v[0]; int jm = 0;
            #pragma unroll
            for (int j = 1; j < 8; ++j) { if (v[j] > m) { m = v[j]; jm = j; } }
            float g = m;
            g = fmaxf(g, __shfl_xor(g, 1));
            g = fmaxf(g, __shfl_xor(g, 2));
            g = fmaxf(g, __shfl_xor(g, 4));
            sum5 += g;
            unsigned long long bl = __ballot(m == g) & gmask;
            int owner = __ffsll(bl) - 1;
            if (lane == owner) v[jm] = -INFINITY;
        }
        if ((tx & 7) == 0) {
            float tv = sum5 / 5.f;
            int lr = (row0 + ty * 4 + rr) & 32767;
            if (half) {
                if (side == 0) { out[O_AATT + lr]  = tv; tatt[lr] = tv; }
                else           { out[O_NAATT + lr] = tv; tatt[2 * 32768 + lr] = tv; }
            } else {
                if (side == 0) { out[O_ANATT + lr] = tv; }
                else           { out[O_NATT + lr]  = tv; tatt[32768 + lr] = tv; }
            }
        }
    }
}

// ---------------- top-33: single-pass rank (== stable top_k, lower index wins ties) ----
__global__ __launch_bounds__(256) void k_topk(const float* __restrict__ tatt, int* __restrict__ idx) {
    __shared__ float vals[512];
    int s = blockIdx.x >> 6, b = blockIdx.x & 63, tid = threadIdx.x;
    const float* src = tatt + (size_t)s * 32768 + b * 512;
    vals[tid] = src[tid]; vals[tid + 256] = src[tid + 256];
    __syncthreads();
    #pragma unroll
    for (int e = 0; e < 2; ++e) {
        int i = tid + e * 256;
        float v = vals[i];
        int rank = 0;
        for (int j = 0; j < 512; j += 4) {
            f32x4 w4 = *(const f32x4*)&vals[j];
            rank += (w4.x > v) || (w4.x == v && (j + 0) < i);
            rank += (w4.y > v) || (w4.y == v && (j + 1) < i);
            rank += (w4.z > v) || (w4.z == v && (j + 2) < i);
            rank += (w4.w > v) || (w4.w == v && (j + 3) < i);
        }
        if (rank < 33) idx[(s * 64 + b) * 40 + rank] = i;
    }
}

// ---------------- gather means of x (192 blocks: one per s,b) ----------------
__global__ __launch_bounds__(256) void k_gather3(const float* __restrict__ x, const int* __restrict__ idx,
                                                 float* __restrict__ gath) {
    __shared__ int il[33];
    int s = blockIdx.x >> 6, b = blockIdx.x & 63, tid = threadIdx.x;
    if (tid < 33) il[tid] = idx[(s * 64 + b) * 40 + tid];
    __syncthreads();
    int srcb = (s == 1) ? b : 64 + b;
    const float* xb = x + (size_t)srcb * 262144;
    int d0 = tid * 2;
    float a0 = 0.f, a1 = 0.f;
    for (int i = 0; i < 33; ++i) {
        const float* p = xb + (size_t)il[i] * 512 + d0;
        a0 += p[0]; a1 += p[1];
    }
    gath[((size_t)s * 64 + b) * 512 + d0]     = a0 / 33.f;
    gath[((size_t)s * 64 + b) * 512 + d0 + 1] = a1 / 33.f;
}

// ---------------- triplet per-b (64 blocks) ----------------
__global__ __launch_bounds__(256) void k_triplet(const float* __restrict__ gath, float* __restrict__ tripb) {
    __shared__ float red[8];
    int b = blockIdx.x, tid = threadIdx.x;
    const float* a = gath + (size_t)(64 + b) * 512;
    const float* p = gath + (size_t)(128 + b) * 512;
    const float* n = gath + (size_t)(b) * 512;
    float a0 = a[tid], a1 = a[tid + 256];
    float p0 = p[tid], p1 = p[tid + 256];
    float n0 = n[tid], n1 = n[tid + 256];
    float na  = sqrtf(blk_sum(a0 * a0 + a1 * a1, red));
    float npv = sqrtf(blk_sum(p0 * p0 + p1 * p1, red));
    float nn  = sqrtf(blk_sum(n0 * n0 + n1 * n1, red));
    float e0 = a0 / na - p0 / npv + 1e-6f, e1 = a1 / na - p1 / npv + 1e-6f;
    float f0 = a0 / na - n0 / nn  + 1e-6f, f1 = a1 / na - n1 / nn  + 1e-6f;
    float dap = sqrtf(blk_sum(e0 * e0 + e1 * e1, red));
    float dan = sqrtf(blk_sum(f0 * f0 + f1 * f1, red));
    if (tid == 0) tripb[b] = fmaxf(dap - dan + 1.f, 0.f);
}

// ---------------- G1: N-half right F_M via MFMA (3 GEMMs K=64) + kl. 512 threads ----------------
__global__ __launch_bounds__(512) void kG1(const u16* __restrict__ attb, const u16* __restrict__ bct,
                                           const u16* __restrict__ pvt, const float* __restrict__ bmu,
                                           const float* __restrict__ bvar, const float* __restrict__ epsv,
                                           float* __restrict__ fm, float* __restrict__ klacc) {
    __shared__ u16 sAA[128 * 32];
    __shared__ u16 sAN[128 * 32];
    __shared__ u16 sBA[128 * 32];
    __shared__ u16 sBN[128 * 32];
    __shared__ u16 sBV[128 * 32];
    __shared__ float red[8];
    int tid = threadIdx.x, lane = tid & 63, wid = tid >> 6;
    int wr = wid >> 2, wc = wid & 3;            // 8 waves: 2 x 4; wave tile 64 rows x 32 cols
    int cl = lane & 15, rq = lane >> 4;
    int m0 = blockIdx.x * 128, c0 = blockIdx.y * 128;

    f32x4 aA[4][2], aN[4][2], aV[4][2];
    #pragma unroll
    for (int i = 0; i < 4; ++i)
        #pragma unroll
        for (int j = 0; j < 2; ++j) { aA[i][j] = (f32x4)0.f; aN[i][j] = (f32x4)0.f; aV[i][j] = (f32x4)0.f; }

    for (int kt = 0; kt < 2; ++kt) {
        stage32_512(attb, m0, 128, kt * 32, sAA, tid);
        stage32_512(attb, m0, 128, 64 + kt * 32, sAN, tid);
        stage32_512(bct, c0, 128, kt * 32, sBA, tid);
        stage32_512(bct, c0, 128, 64 + kt * 32, sBN, tid);
        stage32_512(pvt, c0, 64, kt * 32, sBV, tid);
        __syncthreads();
        s16x8 fA[4], fN[4], bA[2], bN[2], bV[2];
        #pragma unroll
        for (int i = 0; i < 4; ++i) {
            fA[i] = *(const s16x8*)&sAA[(wr * 64 + i * 16 + cl) * 32 + rq * 8];
            fN[i] = *(const s16x8*)&sAN[(wr * 64 + i * 16 + cl) * 32 + rq * 8];
        }
        #pragma unroll
        for (int n = 0; n < 2; ++n) {
            bA[n] = *(const s16x8*)&sBA[(wc * 32 + n * 16 + cl) * 32 + rq * 8];
            bN[n] = *(const s16x8*)&sBN[(wc * 32 + n * 16 + cl) * 32 + rq * 8];
            bV[n] = *(const s16x8*)&sBV[(wc * 32 + n * 16 + cl) * 32 + rq * 8];
        }
        #pragma unroll
        for (int mi = 0; mi < 4; ++mi)
            #pragma unroll
            for (int ni = 0; ni < 2; ++ni) {
                aA[mi][ni] = __builtin_amdgcn_mfma_f32_16x16x32_bf16(fA[mi], bA[ni], aA[mi][ni], 0, 0, 0);
                aN[mi][ni] = __builtin_amdgcn_mfma_f32_16x16x32_bf16(fN[mi], bN[ni], aN[mi][ni], 0, 0, 0);
                aV[mi][ni] = __builtin_amdgcn_mfma_f32_16x16x32_bf16(fN[mi], bV[ni], aV[mi][ni], 0, 0, 0);
            }
        __syncthreads();
    }

    float kll = 0.f;
    #pragma unroll
    for (int mi = 0; mi < 4; ++mi)
        #pragma unroll
        for (int ni = 0; ni < 2; ++ni) {
            int col = c0 + wc * 32 + ni * 16 + cl;
            int rowb = m0 + wr * 64 + mi * 16 + rq * 4;
            float bm = bmu[col], bv = bvar[col];
            #pragma unroll
            for (int q = 0; q < 4; ++q) {
                int row = rowb + q;
                float muN = aN[mi][ni][q] + bm;
                float var = aV[mi][ni][q] + bv;
                float ev = expf(var);
                float muA = aA[mi][ni][q] + bm;
                fm[(size_t)row * 1024 + 512 + col] =
                    muN + epsv[(size_t)row * 512 + col] * sqrtf(ev) + muA;
                kll += 1.f + var - muN * muN - ev;
            }
        }
    #pragma unroll
    for (int o = 32; o; o >>= 1) kll += __shfl_xor(kll, o);
    if (lane == 0) red[wid] = kll;
    __syncthreads();
    if (tid == 0) {
        float s = 0.f;
        #pragma unroll
        for (int i = 0; i < 8; ++i) s += red[i];
        atomicAdd(klacc, s);
    }
}

// ---------------- G3: A-half right F_M via MFMA (K=128). 512 threads ----------------
__global__ __launch_bounds__(512) void kG3(const u16* __restrict__ attb, const u16* __restrict__ bct,
                                           const float* __restrict__ bmu, float* __restrict__ fm) {
    __shared__ u16 sA[128 * 32];
    __shared__ u16 sB[128 * 32];
    int tid = threadIdx.x, lane = tid & 63, wid = tid >> 6;
    int wr = wid >> 2, wc = wid & 3;
    int cl = lane & 15, rq = lane >> 4;
    int m0 = blockIdx.x * 128, c0 = blockIdx.y * 128;

    f32x4 acc[4][2];
    #pragma unroll
    for (int i = 0; i < 4; ++i)
        #pragma unroll
        for (int j = 0; j < 2; ++j) acc[i][j] = (f32x4)0.f;

    for (int kt = 0; kt < 4; ++kt) {
        stage32_512(attb, 32768 + m0, 128, kt * 32, sA, tid);
        stage32_512(bct, c0, 128, kt * 32, sB, tid);
        __syncthreads();
        s16x8 fa[4], fb[2];
        #pragma unroll
        for (int i = 0; i < 4; ++i)
            fa[i] = *(const s16x8*)&sA[(wr * 64 + i * 16 + cl) * 32 + rq * 8];
        #pragma unroll
        for (int n = 0; n < 2; ++n)
            fb[n] = *(const s16x8*)&sB[(wc * 32 + n * 16 + cl) * 32 + rq * 8];
        #pragma unroll
        for (int mi = 0; mi < 4; ++mi)
            #pragma unroll
            for (int ni = 0; ni < 2; ++ni)
                acc[mi][ni] = __builtin_amdgcn_mfma_f32_16x16x32_bf16(fa[mi], fb[ni], acc[mi][ni], 0, 0, 0);
        __syncthreads();
    }
    #pragma unroll
    for (int mi = 0; mi < 4; ++mi)
        #pragma unroll
        for (int ni = 0; ni < 2; ++ni) {
            int col = c0 + wc * 32 + ni * 16 + cl;
            int rowb = 32768 + m0 + wr * 64 + mi * 16 + rq * 4;
            float bm2 = 2.f * bmu[col];
            #pragma unroll
            for (int q = 0; q < 4; ++q)
                fm[(size_t)(rowb + q) * 1024 + 512 + col] = acc[mi][ni][q] + bm2;
        }
}

// ---------------- anchor partial sums (192 blocks: b x 3 segs of 11 rows) ----------------
__global__ __launch_bounds__(256) void k_gather2a(const int* __restrict__ idx, const u16* __restrict__ attb,
                                                  const float* __restrict__ pnm, const float* __restrict__ pnv,
                                                  const float* __restrict__ bmu, const float* __restrict__ bvar,
                                                  const float* __restrict__ epsv, float* __restrict__ SUM) {
    __shared__ float arow[64];
    int blk = blockIdx.x, b = blk / 3, seg = blk % 3;
    int tid = threadIdx.x;
    float s0 = 0.f, s1 = 0.f;
    for (int i = seg * 11; i < seg * 11 + 11; ++i) {
        int t = idx[(64 + b) * 40 + i];   // N_idx
        size_t r = (size_t)b * 512 + t;
        __syncthreads();
        if (tid < 64) arow[tid] = bf2f(attb[r * 128 + 64 + tid]);
        __syncthreads();
        float mu0 = bmu[tid], mu1 = bmu[tid + 256];
        float v0 = bvar[tid], v1 = bvar[tid + 256];
        for (int k = 0; k < 64; ++k) {
            float a = arow[k];
            mu0 += a * pnm[(size_t)k * 512 + tid];
            mu1 += a * pnm[(size_t)k * 512 + tid + 256];
            v0  += a * pnv[(size_t)k * 512 + tid];
            v1  += a * pnv[(size_t)k * 512 + tid + 256];
        }
        s0 += mu0 + epsv[r * 512 + tid]       * sqrtf(expf(v0));
        s1 += mu1 + epsv[r * 512 + tid + 256] * sqrtf(expf(v1));
    }
    atomicAdd(&SUM[(size_t)b * 512 + tid], s0);
    atomicAdd(&SUM[(size_t)b * 512 + tid + 256], s1);
}

// ---------------- anchor norms from SUM ----------------
__global__ __launch_bounds__(256) void k_norm2a(const float* __restrict__ SUM, float* __restrict__ norms) {
    __shared__ float red[8];
    int b = blockIdx.x, tid = threadIdx.x;
    float s0 = SUM[(size_t)b * 512 + tid] / 33.f;
    float s1 = SUM[(size_t)b * 512 + tid + 256] / 33.f;
    float ss = blk_sum(s0 * s0 + s1 * s1, red);
    if (tid == 0) norms[b] = sqrtf(ss);
}

// ---------------- negative norms: mean-att @ P_A_mu + b_mu (linearity) ----------------
__global__ __launch_bounds__(256) void k_gather2b(const int* __restrict__ idx, const u16* __restrict__ attb,
                                                  const float* __restrict__ pam, const float* __restrict__ bmu,
                                                  float* __restrict__ norms) {
    __shared__ float meanA[64];
    __shared__ float red[8];
    int b = blockIdx.x, tid = threadIdx.x;
    if (tid < 64) {
        float s = 0.f;
        for (int i = 0; i < 33; ++i) {
            int t = idx[b * 40 + i];      // A_idx
            s += bf2f(attb[(size_t)(32768 + b * 512 + t) * 128 + tid]);
        }
        meanA[tid] = s * (1.f / 33.f);
    }
    __syncthreads();
    float s0 = bmu[tid], s1 = bmu[tid + 256];
    #pragma unroll 4
    for (int k = 0; k < 64; ++k) {
        float m = meanA[k];
        s0 += m * pam[(size_t)k * 512 + tid];
        s1 += m * pam[(size_t)k * 512 + tid + 256];
    }
    float ss = blk_sum(s0 * s0 + s1 * s1, red);
    if (tid == 0) norms[64 + b] = sqrtf(ss);
}

// ---------------- finalize: triplet + distance + kl ----------------
__global__ __launch_bounds__(64) void k_final(const float* __restrict__ norms, const float* __restrict__ klacc,
                                              const float* __restrict__ tripb, float* __restrict__ out) {
    int tid = threadIdx.x;
    float v = fmaxf(100.f - norms[64 + tid] + norms[tid], 0.f);
    float t = tripb[tid];
    #pragma unroll
    for (int o = 32; o; o >>= 1) { v += __shfl_xor(v, o); t += __shfl_xor(t, o); }
    if (tid == 0) {
        out[O_DIST] = v / 64.f;
        out[O_TRIP] = t / 64.f;
        out[O_KL]   = -0.5f * (*klacc) / 32768.f;
    }
}

extern "C" void kernel_launch(void* const* d_in, const int* in_sizes, int n_in,
                              void* d_out, int out_size, void* d_ws, size_t ws_size,
                              hipStream_t stream) {
    const float* x    = (const float*)d_in[0];
    const float* Amem = (const float*)d_in[1];
    const float* Nmem = (const float*)d_in[2];
    const float* Wmu  = (const float*)d_in[3];
    const float* bmu  = (const float*)d_in[4];
    const float* Wvar = (const float*)d_in[5];
    const float* bvar = (const float*)d_in[6];
    const float* eps  = (const float*)d_in[7];
    float* out = (float*)d_out;
    char* ws = (char*)d_ws;
    const u16* attb  = (const u16*)(ws + WS_ATTB);
    const u16* bct   = (const u16*)(ws + WS_BCT);
    const u16* pvt   = (const u16*)(ws + WS_PVT);
    const float* pam = (const float*)(ws + WS_PAM);
    const float* pnm = (const float*)(ws + WS_PNM);
    const float* pnv = (const float*)(ws + WS_PNV);
    const int* idx   = (const int*)(ws + WS_IDX);

    k_prep<<<256, 256, 0, stream>>>(Amem, Nmem, ws);
    k_proj<<<192, 256, 0, stream>>>(Amem, Nmem, Wmu, Wvar,
                                    (float*)(ws + WS_PAM), (float*)(ws + WS_PNM), (float*)(ws + WS_PNV),
                                    (u16*)(ws + WS_BCT), (u16*)(ws + WS_PVT));
    k_dots<<<1024, 256, 0, stream>>>(x, ws, out);
    k_topk<<<192, 256, 0, stream>>>((const float*)(ws + WS_TATT), (int*)(ws + WS_IDX));
    k_gather3<<<192, 256, 0, stream>>>(x, idx, (float*)(ws + WS_GATH));
    k_triplet<<<64, 256, 0, stream>>>((const float*)(ws + WS_GATH), (float*)(ws + WS_TRIPB));
    kG1<<<dim3(256, 4), 512, 0, stream>>>(attb, bct, pvt, bmu, bvar, eps, out, (float*)(ws + WS_KL));
    kG3<<<dim3(256, 4), 512, 0, stream>>>(attb, bct, bmu, out);
    k_gather2a<<<192, 256, 0, stream>>>(idx, attb, pnm, pnv, bmu, bvar, eps, (float*)(ws + WS_SUM));
    k_norm2a<<<64, 256, 0, stream>>>((const float*)(ws + WS_SUM), (float*)(ws + WS_NORM));
    k_gather2b<<<64, 256, 0, stream>>>(idx, attb, pam, bmu, (float*)(ws + WS_NORM));
    k_final<<<1, 64, 0, stream>>>((const float*)(ws + WS_NORM), (const float*)(ws + WS_KL),
                                  (const float*)(ws + WS_TRIPB), out);
}

// Round 12
// 313.743 us; speedup vs baseline: 2.2821x; 1.1047x over previous
//
#include <hip/hip_runtime.h>
#include <hip/hip_bf16.h>
#include <math.h>

// B=128, T=512, D=512, K=64; mid=64; rows per half = 32768. f32 in/out.
typedef unsigned short u16;
typedef __attribute__((ext_vector_type(4))) float f32x4;
typedef __attribute__((ext_vector_type(8))) short s16x8;

// ---------------- output offsets (f32 elements) ----------------
#define O_FM    0ULL
#define O_TRIP  67108864ULL
#define O_KL    67108865ULL
#define O_DIST  67108866ULL
#define O_AATT  67108867ULL
#define O_NATT  67141635ULL
#define O_ANATT 67174403ULL
#define O_NAATT 67207171ULL

// ---------------- ws offsets (bytes), total ~18.6 MB (ws_size ~1 GB) ----------------
#define WS_ATTB  0ULL          // att bf16 [65536][128] (k<64: vs Amem, k>=64: vs Nmem)
#define WS_BCT   16777216ULL   // bf16 [512 n][128 k]: k<64 = pam^T, k>=64 = pnm^T
#define WS_PVT   16908288ULL   // bf16 [512 n][64 k] = pnv^T
#define WS_PAM   16973824ULL   // f32 [64][512]  (Amem @ W_mu)
#define WS_PNM   17104896ULL   // f32 [64][512]  (Nmem @ W_mu)
#define WS_PNV   17235968ULL   // f32 [64][512]  (Nmem @ W_var)
#define WS_MBH   17367040ULL   // bf16 [128 k][512 d] mem hi  (k<64 Amem, else Nmem)
#define WS_MBL   17498112ULL   // bf16 [128 k][512 d] mem lo  (residual)
#define WS_TATT  17629184ULL   // f32 [3][32768] (0=A_att,1=N_att,2=N_Aatt)
#define WS_IDX   18022400ULL   // int [3][64][40]
#define WS_GATH  18053120ULL   // f32 [3][64][512]
#define WS_NORM  18446336ULL   // f32 [128]
#define WS_KL    18446848ULL   // f32 accumulator
#define WS_TRIPB 18447360ULL   // f32 [64]
#define WS_SUM   18447616ULL   // f32 [64][512] anchor partial sums

__device__ __forceinline__ u16 f2bf(float f) {
    union { float f; unsigned int u; } c; c.f = f;
    unsigned int r = c.u + 0x7fffu + ((c.u >> 16) & 1u);
    return (u16)(r >> 16);
}
__device__ __forceinline__ float bf2f(u16 h) {
    union { unsigned int u; float f; } c; c.u = ((unsigned int)h) << 16;
    return c.f;
}

__device__ __forceinline__ float blk_sum(float v, float* red) {
    #pragma unroll
    for (int o = 32; o; o >>= 1) v += __shfl_xor(v, o);
    int tid = threadIdx.x;
    if ((tid & 63) == 0) red[tid >> 6] = v;
    __syncthreads();
    float r = red[0] + red[1] + red[2] + red[3];
    __syncthreads();
    return r;
}

// stage a 128x32 bf16 tile into LDS linearly -- 512-thread version (one 16B load each)
__device__ __forceinline__ void stage32_512(const u16* __restrict__ g, int row0, int ld, int k0,
                                            u16* s, int tid) {
    const u16* src = g + (size_t)(row0 + (tid >> 2)) * ld + k0 + (tid & 3) * 8;
    __builtin_amdgcn_global_load_lds((const __attribute__((address_space(1))) void*)src,
                                     (__attribute__((address_space(3))) void*)(s + tid * 8),
                                     16, 0, 0);
}

// ---------------- prep: mem hi/lo bf16 split + zero KL/SUM ----------------
__global__ __launch_bounds__(256) void k_prep(const float* __restrict__ Amem, const float* __restrict__ Nmem,
                                              char* __restrict__ ws) {
    int i = blockIdx.x * 256 + threadIdx.x;
    if (i == 0) *(float*)(ws + WS_KL) = 0.f;
    if (i < 32768) ((float*)(ws + WS_SUM))[i] = 0.f;
    int k = i >> 9, d = i & 511;
    float v = (k < 64) ? Amem[(size_t)k * 512 + d] : Nmem[(size_t)(k - 64) * 512 + d];
    u16 h = f2bf(v);
    ((u16*)(ws + WS_MBH))[i] = h;
    ((u16*)(ws + WS_MBL))[i] = f2bf(v - bf2f(h));
}

// ---------------- proj: P = mem @ W, f32 [k][n] + bf16 transposed ----------------
__global__ __launch_bounds__(256) void k_proj(const float* __restrict__ Amem, const float* __restrict__ Nmem,
                                              const float* __restrict__ Wmu, const float* __restrict__ Wvar,
                                              float* __restrict__ pam, float* __restrict__ pnm,
                                              float* __restrict__ pnv, u16* __restrict__ bct,
                                              u16* __restrict__ pvt) {
    __shared__ float mr[512];
    int mat = blockIdx.x >> 6, k = blockIdx.x & 63, tid = threadIdx.x;
    const float* mrow = ((mat == 0) ? Amem : Nmem) + (size_t)k * 512;
    const float* W = (mat == 2) ? Wvar : Wmu;
    mr[tid] = mrow[tid]; mr[tid + 256] = mrow[tid + 256];
    __syncthreads();
    float s0 = 0.f, s1 = 0.f;
    for (int d = 0; d < 512; ++d) {
        float m = mr[d];
        s0 += m * W[(size_t)d * 512 + tid];
        s1 += m * W[(size_t)d * 512 + tid + 256];
    }
    if (mat == 0) {
        pam[(size_t)k * 512 + tid] = s0; pam[(size_t)k * 512 + tid + 256] = s1;
        bct[(size_t)tid * 128 + k] = f2bf(s0); bct[(size_t)(tid + 256) * 128 + k] = f2bf(s1);
    } else if (mat == 1) {
        pnm[(size_t)k * 512 + tid] = s0; pnm[(size_t)k * 512 + tid + 256] = s1;
        bct[(size_t)tid * 128 + 64 + k] = f2bf(s0); bct[(size_t)(tid + 256) * 128 + 64 + k] = f2bf(s1);
    } else {
        pnv[(size_t)k * 512 + tid] = s0; pnv[(size_t)k * 512 + tid + 256] = s1;
        pvt[(size_t)tid * 64 + k] = f2bf(s0); pvt[(size_t)(tid + 256) * 64 + k] = f2bf(s1);
    }
}

// ---------------- dots via split-bf16 MFMA: att = sigmoid((xh+xl)@(mh+ml)^T / sqrt(512)) ----
// dot = xh.mh + xh.ml + xl.mh (xl.ml dropped, ~2^-18 relative). 8 waves x 16-row tiles,
// 128 cols. Also writes F_M left half (exact f32 copy of x) during staging.
__global__ __launch_bounds__(512) void k_dots(const float* __restrict__ x, char* __restrict__ ws,
                                              float* __restrict__ out) {
    __shared__ u16 sXh[128 * 32];
    __shared__ u16 sXl[128 * 32];
    __shared__ u16 sBh[128 * 32];
    __shared__ u16 sBl[128 * 32];

    int tid = threadIdx.x;
    int row0 = blockIdx.x * 128;
    const u16* mbh = (const u16*)(ws + WS_MBH);
    const u16* mbl = (const u16*)(ws + WS_MBL);
    u16* attb = (u16*)(ws + WS_ATTB);
    int lane = tid & 63, wid = tid >> 6;
    int cl = lane & 15, rq = lane >> 4;

    f32x4 acc[8];
    #pragma unroll
    for (int i = 0; i < 8; ++i) acc[i] = (f32x4)0.f;

    for (int dc = 0; dc < 16; ++dc) {
        int d0 = dc * 32;
        {   // stage x chunk [128 rows][32 d]: F_M copy + hi/lo bf16 into LDS
            int r = tid >> 2, q4 = tid & 3;
            const float* sp = x + (size_t)(row0 + r) * 512 + d0 + q4 * 8;
            float* op = out + (size_t)(row0 + r) * 1024 + d0 + q4 * 8;
            f32x4 v0 = *(const f32x4*)(sp);
            f32x4 v1 = *(const f32x4*)(sp + 4);
            *(f32x4*)(op) = v0;
            *(f32x4*)(op + 4) = v1;
            s16x8 hs, ls;
            #pragma unroll
            for (int j = 0; j < 4; ++j) {
                u16 h0 = f2bf(v0[j]); hs[j] = (short)h0; ls[j] = (short)f2bf(v0[j] - bf2f(h0));
                u16 h1 = f2bf(v1[j]); hs[4 + j] = (short)h1; ls[4 + j] = (short)f2bf(v1[j] - bf2f(h1));
            }
            *(s16x8*)&sXh[r * 32 + q4 * 8] = hs;
            *(s16x8*)&sXl[r * 32 + q4 * 8] = ls;
        }
        stage32_512(mbh, 0, 512, d0, sBh, tid);
        stage32_512(mbl, 0, 512, d0, sBl, tid);
        __syncthreads();
        s16x8 axh = *(const s16x8*)&sXh[(wid * 16 + cl) * 32 + rq * 8];
        s16x8 axl = *(const s16x8*)&sXl[(wid * 16 + cl) * 32 + rq * 8];
        #pragma unroll
        for (int ni = 0; ni < 8; ++ni) {
            s16x8 bh = *(const s16x8*)&sBh[(ni * 16 + cl) * 32 + rq * 8];
            s16x8 bl = *(const s16x8*)&sBl[(ni * 16 + cl) * 32 + rq * 8];
            acc[ni] = __builtin_amdgcn_mfma_f32_16x16x32_bf16(axh, bh, acc[ni], 0, 0, 0);
            acc[ni] = __builtin_amdgcn_mfma_f32_16x16x32_bf16(axh, bl, acc[ni], 0, 0, 0);
            acc[ni] = __builtin_amdgcn_mfma_f32_16x16x32_bf16(axl, bh, acc[ni], 0, 0, 0);
        }
        __syncthreads();
    }

    // sigmoid + attb write; acc[ni][q] -> att value at row=row0+wid*16+rq*4+q, col=ni*16+cl
    #pragma unroll
    for (int ni = 0; ni < 8; ++ni) {
        #pragma unroll
        for (int q = 0; q < 4; ++q) {
            float logit = acc[ni][q] * 0.044194173824159216f;  // 1/sqrt(512)
            float av = 1.f / (1.f + expf(-logit));
            acc[ni][q] = av;
            attb[(size_t)(row0 + wid * 16 + rq * 4 + q) * 128 + ni * 16 + cl] = f2bf(av);
        }
    }

    // t_att: top-5-of-64 per (row, side) via 16-lane-group reduce + knockout
    unsigned long long gmask = 0xFFFFull << (lane & 48);
    float* tatt = (float*)(ws + WS_TATT);
    int half = row0 >> 15;
    #pragma unroll
    for (int q = 0; q < 4; ++q) {
        #pragma unroll
        for (int side = 0; side < 2; ++side) {
            float v0 = acc[side * 4 + 0][q], v1 = acc[side * 4 + 1][q];
            float v2 = acc[side * 4 + 2][q], v3 = acc[side * 4 + 3][q];
            float sum5 = 0.f;
            #pragma unroll
            for (int it = 0; it < 5; ++it) {
                float m = v0; int jm = 0;
                if (v1 > m) { m = v1; jm = 1; }
                if (v2 > m) { m = v2; jm = 2; }
                if (v3 > m) { m = v3; jm = 3; }
                float g = m;
                g = fmaxf(g, __shfl_xor(g, 1));
                g = fmaxf(g, __shfl_xor(g, 2));
                g = fmaxf(g, __shfl_xor(g, 4));
                g = fmaxf(g, __shfl_xor(g, 8));
                sum5 += g;
                unsigned long long bl = __ballot(m == g) & gmask;
                int owner = __ffsll(bl) - 1;
                if (lane == owner) {
                    if (jm == 0) v0 = -INFINITY;
                    else if (jm == 1) v1 = -INFINITY;
                    else if (jm == 2) v2 = -INFINITY;
                    else v3 = -INFINITY;
                }
            }
            if (cl == 0) {
                float tv = sum5 / 5.f;
                int lr = (row0 + wid * 16 + rq * 4 + q) & 32767;
                if (half) {
                    if (side == 0) { out[O_AATT + lr]  = tv; tatt[lr] = tv; }
                    else           { out[O_NAATT + lr] = tv; tatt[2 * 32768 + lr] = tv; }
                } else {
                    if (side == 0) { out[O_ANATT + lr] = tv; }
                    else           { out[O_NATT + lr]  = tv; tatt[32768 + lr] = tv; }
                }
            }
        }
    }
}

// ---------------- top-33: single-pass rank (== stable top_k, lower index wins ties) ----
__global__ __launch_bounds__(256) void k_topk(const float* __restrict__ tatt, int* __restrict__ idx) {
    __shared__ float vals[512];
    int s = blockIdx.x >> 6, b = blockIdx.x & 63, tid = threadIdx.x;
    const float* src = tatt + (size_t)s * 32768 + b * 512;
    vals[tid] = src[tid]; vals[tid + 256] = src[tid + 256];
    __syncthreads();
    #pragma unroll
    for (int e = 0; e < 2; ++e) {
        int i = tid + e * 256;
        float v = vals[i];
        int rank = 0;
        for (int j = 0; j < 512; j += 4) {
            f32x4 w4 = *(const f32x4*)&vals[j];
            rank += (w4.x > v) || (w4.x == v && (j + 0) < i);
            rank += (w4.y > v) || (w4.y == v && (j + 1) < i);
            rank += (w4.z > v) || (w4.z == v && (j + 2) < i);
            rank += (w4.w > v) || (w4.w == v && (j + 3) < i);
        }
        if (rank < 33) idx[(s * 64 + b) * 40 + rank] = i;
    }
}

// ---------------- gather means of x (192 blocks: one per s,b) ----------------
__global__ __launch_bounds__(256) void k_gather3(const float* __restrict__ x, const int* __restrict__ idx,
                                                 float* __restrict__ gath) {
    __shared__ int il[33];
    int s = blockIdx.x >> 6, b = blockIdx.x & 63, tid = threadIdx.x;
    if (tid < 33) il[tid] = idx[(s * 64 + b) * 40 + tid];
    __syncthreads();
    int srcb = (s == 1) ? b : 64 + b;
    const float* xb = x + (size_t)srcb * 262144;
    int d0 = tid * 2;
    float a0 = 0.f, a1 = 0.f;
    for (int i = 0; i < 33; ++i) {
        const float* p = xb + (size_t)il[i] * 512 + d0;
        a0 += p[0]; a1 += p[1];
    }
    gath[((size_t)s * 64 + b) * 512 + d0]     = a0 / 33.f;
    gath[((size_t)s * 64 + b) * 512 + d0 + 1] = a1 / 33.f;
}

// ---------------- triplet per-b (64 blocks) ----------------
__global__ __launch_bounds__(256) void k_triplet(const float* __restrict__ gath, float* __restrict__ tripb) {
    __shared__ float red[8];
    int b = blockIdx.x, tid = threadIdx.x;
    const float* a = gath + (size_t)(64 + b) * 512;
    const float* p = gath + (size_t)(128 + b) * 512;
    const float* n = gath + (size_t)(b) * 512;
    float a0 = a[tid], a1 = a[tid + 256];
    float p0 = p[tid], p1 = p[tid + 256];
    float n0 = n[tid], n1 = n[tid + 256];
    float na  = sqrtf(blk_sum(a0 * a0 + a1 * a1, red));
    float npv = sqrtf(blk_sum(p0 * p0 + p1 * p1, red));
    float nn  = sqrtf(blk_sum(n0 * n0 + n1 * n1, red));
    float e0 = a0 / na - p0 / npv + 1e-6f, e1 = a1 / na - p1 / npv + 1e-6f;
    float f0 = a0 / na - n0 / nn  + 1e-6f, f1 = a1 / na - n1 / nn  + 1e-6f;
    float dap = sqrtf(blk_sum(e0 * e0 + e1 * e1, red));
    float dan = sqrtf(blk_sum(f0 * f0 + f1 * f1, red));
    if (tid == 0) tripb[b] = fmaxf(dap - dan + 1.f, 0.f);
}

// ---------------- G1: N-half right F_M via MFMA (3 GEMMs K=64) + kl. 512 threads ----------------
__global__ __launch_bounds__(512) void kG1(const u16* __restrict__ attb, const u16* __restrict__ bct,
                                           const u16* __restrict__ pvt, const float* __restrict__ bmu,
                                           const float* __restrict__ bvar, const float* __restrict__ epsv,
                                           float* __restrict__ fm, float* __restrict__ klacc) {
    __shared__ u16 sAA[128 * 32];
    __shared__ u16 sAN[128 * 32];
    __shared__ u16 sBA[128 * 32];
    __shared__ u16 sBN[128 * 32];
    __shared__ u16 sBV[128 * 32];
    __shared__ float red[8];
    int tid = threadIdx.x, lane = tid & 63, wid = tid >> 6;
    int wr = wid >> 2, wc = wid & 3;            // 8 waves: 2 x 4; wave tile 64 rows x 32 cols
    int cl = lane & 15, rq = lane >> 4;
    int m0 = blockIdx.x * 128, c0 = blockIdx.y * 128;

    f32x4 aA[4][2], aN[4][2], aV[4][2];
    #pragma unroll
    for (int i = 0; i < 4; ++i)
        #pragma unroll
        for (int j = 0; j < 2; ++j) { aA[i][j] = (f32x4)0.f; aN[i][j] = (f32x4)0.f; aV[i][j] = (f32x4)0.f; }

    for (int kt = 0; kt < 2; ++kt) {
        stage32_512(attb, m0, 128, kt * 32, sAA, tid);
        stage32_512(attb, m0, 128, 64 + kt * 32, sAN, tid);
        stage32_512(bct, c0, 128, kt * 32, sBA, tid);
        stage32_512(bct, c0, 128, 64 + kt * 32, sBN, tid);
        stage32_512(pvt, c0, 64, kt * 32, sBV, tid);
        __syncthreads();
        s16x8 fA[4], fN[4], bA[2], bN[2], bV[2];
        #pragma unroll
        for (int i = 0; i < 4; ++i) {
            fA[i] = *(const s16x8*)&sAA[(wr * 64 + i * 16 + cl) * 32 + rq * 8];
            fN[i] = *(const s16x8*)&sAN[(wr * 64 + i * 16 + cl) * 32 + rq * 8];
        }
        #pragma unroll
        for (int n = 0; n < 2; ++n) {
            bA[n] = *(const s16x8*)&sBA[(wc * 32 + n * 16 + cl) * 32 + rq * 8];
            bN[n] = *(const s16x8*)&sBN[(wc * 32 + n * 16 + cl) * 32 + rq * 8];
            bV[n] = *(const s16x8*)&sBV[(wc * 32 + n * 16 + cl) * 32 + rq * 8];
        }
        #pragma unroll
        for (int mi = 0; mi < 4; ++mi)
            #pragma unroll
            for (int ni = 0; ni < 2; ++ni) {
                aA[mi][ni] = __builtin_amdgcn_mfma_f32_16x16x32_bf16(fA[mi], bA[ni], aA[mi][ni], 0, 0, 0);
                aN[mi][ni] = __builtin_amdgcn_mfma_f32_16x16x32_bf16(fN[mi], bN[ni], aN[mi][ni], 0, 0, 0);
                aV[mi][ni] = __builtin_amdgcn_mfma_f32_16x16x32_bf16(fN[mi], bV[ni], aV[mi][ni], 0, 0, 0);
            }
        __syncthreads();
    }

    float kll = 0.f;
    #pragma unroll
    for (int mi = 0; mi < 4; ++mi)
        #pragma unroll
        for (int ni = 0; ni < 2; ++ni) {
            int col = c0 + wc * 32 + ni * 16 + cl;
            int rowb = m0 + wr * 64 + mi * 16 + rq * 4;
            float bm = bmu[col], bv = bvar[col];
            #pragma unroll
            for (int q = 0; q < 4; ++q) {
                int row = rowb + q;
                float muN = aN[mi][ni][q] + bm;
                float var = aV[mi][ni][q] + bv;
                float ev = expf(var);
                float muA = aA[mi][ni][q] + bm;
                fm[(size_t)row * 1024 + 512 + col] =
                    muN + epsv[(size_t)row * 512 + col] * sqrtf(ev) + muA;
                kll += 1.f + var - muN * muN - ev;
            }
        }
    #pragma unroll
    for (int o = 32; o; o >>= 1) kll += __shfl_xor(kll, o);
    if (lane == 0) red[wid] = kll;
    __syncthreads();
    if (tid == 0) {
        float s = 0.f;
        #pragma unroll
        for (int i = 0; i < 8; ++i) s += red[i];
        atomicAdd(klacc, s);
    }
}

// ---------------- G3: A-half right F_M via MFMA (K=128). 512 threads ----------------
__global__ __launch_bounds__(512) void kG3(const u16* __restrict__ attb, const u16* __restrict__ bct,
                                           const float* __restrict__ bmu, float* __restrict__ fm) {
    __shared__ u16 sA[128 * 32];
    __shared__ u16 sB[128 * 32];
    int tid = threadIdx.x, lane = tid & 63, wid = tid >> 6;
    int wr = wid >> 2, wc = wid & 3;
    int cl = lane & 15, rq = lane >> 4;
    int m0 = blockIdx.x * 128, c0 = blockIdx.y * 128;

    f32x4 acc[4][2];
    #pragma unroll
    for (int i = 0; i < 4; ++i)
        #pragma unroll
        for (int j = 0; j < 2; ++j) acc[i][j] = (f32x4)0.f;

    for (int kt = 0; kt < 4; ++kt) {
        stage32_512(attb, 32768 + m0, 128, kt * 32, sA, tid);
        stage32_512(bct, c0, 128, kt * 32, sB, tid);
        __syncthreads();
        s16x8 fa[4], fb[2];
        #pragma unroll
        for (int i = 0; i < 4; ++i)
            fa[i] = *(const s16x8*)&sA[(wr * 64 + i * 16 + cl) * 32 + rq * 8];
        #pragma unroll
        for (int n = 0; n < 2; ++n)
            fb[n] = *(const s16x8*)&sB[(wc * 32 + n * 16 + cl) * 32 + rq * 8];
        #pragma unroll
        for (int mi = 0; mi < 4; ++mi)
            #pragma unroll
            for (int ni = 0; ni < 2; ++ni)
                acc[mi][ni] = __builtin_amdgcn_mfma_f32_16x16x32_bf16(fa[mi], fb[ni], acc[mi][ni], 0, 0, 0);
        __syncthreads();
    }
    #pragma unroll
    for (int mi = 0; mi < 4; ++mi)
        #pragma unroll
        for (int ni = 0; ni < 2; ++ni) {
            int col = c0 + wc * 32 + ni * 16 + cl;
            int rowb = 32768 + m0 + wr * 64 + mi * 16 + rq * 4;
            float bm2 = 2.f * bmu[col];
            #pragma unroll
            for (int q = 0; q < 4; ++q)
                fm[(size_t)(rowb + q) * 1024 + 512 + col] = acc[mi][ni][q] + bm2;
        }
}

// ---------------- anchor partial sums (192 blocks: b x 3 segs of 11 rows) ----------------
__global__ __launch_bounds__(256) void k_gather2a(const int* __restrict__ idx, const u16* __restrict__ attb,
                                                  const float* __restrict__ pnm, const float* __restrict__ pnv,
                                                  const float* __restrict__ bmu, const float* __restrict__ bvar,
                                                  const float* __restrict__ epsv, float* __restrict__ SUM) {
    __shared__ float arow[64];
    int blk = blockIdx.x, b = blk / 3, seg = blk % 3;
    int tid = threadIdx.x;
    float s0 = 0.f, s1 = 0.f;
    for (int i = seg * 11; i < seg * 11 + 11; ++i) {
        int t = idx[(64 + b) * 40 + i];   // N_idx
        size_t r = (size_t)b * 512 + t;
        __syncthreads();
        if (tid < 64) arow[tid] = bf2f(attb[r * 128 + 64 + tid]);
        __syncthreads();
        float mu0 = bmu[tid], mu1 = bmu[tid + 256];
        float v0 = bvar[tid], v1 = bvar[tid + 256];
        for (int k = 0; k < 64; ++k) {
            float a = arow[k];
            mu0 += a * pnm[(size_t)k * 512 + tid];
            mu1 += a * pnm[(size_t)k * 512 + tid + 256];
            v0  += a * pnv[(size_t)k * 512 + tid];
            v1  += a * pnv[(size_t)k * 512 + tid + 256];
        }
        s0 += mu0 + epsv[r * 512 + tid]       * sqrtf(expf(v0));
        s1 += mu1 + epsv[r * 512 + tid + 256] * sqrtf(expf(v1));
    }
    atomicAdd(&SUM[(size_t)b * 512 + tid], s0);
    atomicAdd(&SUM[(size_t)b * 512 + tid + 256], s1);
}

// ---------------- anchor norms from SUM ----------------
__global__ __launch_bounds__(256) void k_norm2a(const float* __restrict__ SUM, float* __restrict__ norms) {
    __shared__ float red[8];
    int b = blockIdx.x, tid = threadIdx.x;
    float s0 = SUM[(size_t)b * 512 + tid] / 33.f;
    float s1 = SUM[(size_t)b * 512 + tid + 256] / 33.f;
    float ss = blk_sum(s0 * s0 + s1 * s1, red);
    if (tid == 0) norms[b] = sqrtf(ss);
}

// ---------------- negative norms: mean-att @ P_A_mu + b_mu (linearity) ----------------
__global__ __launch_bounds__(256) void k_gather2b(const int* __restrict__ idx, const u16* __restrict__ attb,
                                                  const float* __restrict__ pam, const float* __restrict__ bmu,
                                                  float* __restrict__ norms) {
    __shared__ float meanA[64];
    __shared__ float red[8];
    int b = blockIdx.x, tid = threadIdx.x;
    if (tid < 64) {
        float s = 0.f;
        for (int i = 0; i < 33; ++i) {
            int t = idx[b * 40 + i];      // A_idx
            s += bf2f(attb[(size_t)(32768 + b * 512 + t) * 128 + tid]);
        }
        meanA[tid] = s * (1.f / 33.f);
    }
    __syncthreads();
    float s0 = bmu[tid], s1 = bmu[tid + 256];
    #pragma unroll 4
    for (int k = 0; k < 64; ++k) {
        float m = meanA[k];
        s0 += m * pam[(size_t)k * 512 + tid];
        s1 += m * pam[(size_t)k * 512 + tid + 256];
    }
    float ss = blk_sum(s0 * s0 + s1 * s1, red);
    if (tid == 0) norms[64 + b] = sqrtf(ss);
}

// ---------------- finalize: triplet + distance + kl ----------------
__global__ __launch_bounds__(64) void k_final(const float* __restrict__ norms, const float* __restrict__ klacc,
                                              const float* __restrict__ tripb, float* __restrict__ out) {
    int tid = threadIdx.x;
    float v = fmaxf(100.f - norms[64 + tid] + norms[tid], 0.f);
    float t = tripb[tid];
    #pragma unroll
    for (int o = 32; o; o >>= 1) { v += __shfl_xor(v, o); t += __shfl_xor(t, o); }
    if (tid == 0) {
        out[O_DIST] = v / 64.f;
        out[O_TRIP] = t / 64.f;
        out[O_KL]   = -0.5f * (*klacc) / 32768.f;
    }
}

extern "C" void kernel_launch(void* const* d_in, const int* in_sizes, int n_in,
                              void* d_out, int out_size, void* d_ws, size_t ws_size,
                              hipStream_t stream) {
    const float* x    = (const float*)d_in[0];
    const float* Amem = (const float*)d_in[1];
    const float* Nmem = (const float*)d_in[2];
    const float* Wmu  = (const float*)d_in[3];
    const float* bmu  = (const float*)d_in[4];
    const float* Wvar = (const float*)d_in[5];
    const float* bvar = (const float*)d_in[6];
    const float* eps  = (const float*)d_in[7];
    float* out = (float*)d_out;
    char* ws = (char*)d_ws;
    const u16* attb  = (const u16*)(ws + WS_ATTB);
    const u16* bct   = (const u16*)(ws + WS_BCT);
    const u16* pvt   = (const u16*)(ws + WS_PVT);
    const float* pam = (const float*)(ws + WS_PAM);
    const float* pnm = (const float*)(ws + WS_PNM);
    const float* pnv = (const float*)(ws + WS_PNV);
    const int* idx   = (const int*)(ws + WS_IDX);

    k_prep<<<256, 256, 0, stream>>>(Amem, Nmem, ws);
    k_proj<<<192, 256, 0, stream>>>(Amem, Nmem, Wmu, Wvar,
                                    (float*)(ws + WS_PAM), (float*)(ws + WS_PNM), (float*)(ws + WS_PNV),
                                    (u16*)(ws + WS_BCT), (u16*)(ws + WS_PVT));
    k_dots<<<512, 512, 0, stream>>>(x, ws, out);
    k_topk<<<192, 256, 0, stream>>>((const float*)(ws + WS_TATT), (int*)(ws + WS_IDX));
    k_gather3<<<192, 256, 0, stream>>>(x, idx, (float*)(ws + WS_GATH));
    k_triplet<<<64, 256, 0, stream>>>((const float*)(ws + WS_GATH), (float*)(ws + WS_TRIPB));
    kG1<<<dim3(256, 4), 512, 0, stream>>>(attb, bct, pvt, bmu, bvar, eps, out, (float*)(ws + WS_KL));
    kG3<<<dim3(256, 4), 512, 0, stream>>>(attb, bct, bmu, out);
    k_gather2a<<<192, 256, 0, stream>>>(idx, attb, pnm, pnv, bmu, bvar, eps, (float*)(ws + WS_SUM));
    k_norm2a<<<64, 256, 0, stream>>>((const float*)(ws + WS_SUM), (float*)(ws + WS_NORM));
    k_gather2b<<<64, 256, 0, stream>>>(idx, attb, pam, bmu, (float*)(ws + WS_NORM));
    k_final<<<1, 64, 0, stream>>>((const float*)(ws + WS_NORM), (const float*)(ws + WS_KL),
                                  (const float*)(ws + WS_TRIPB), out);
}

// Round 13
// 272.415 us; speedup vs baseline: 2.6283x; 1.1517x over previous
//
#include <hip/hip_runtime.h>
#include <hip/hip_bf16.h>
#include <math.h>

// B=128, T=512, D=512, K=64; mid=64; rows per half = 32768. f32 in/out.
typedef unsigned short u16;
typedef __attribute__((ext_vector_type(4))) float f32x4;
typedef __attribute__((ext_vector_type(8))) short s16x8;

// ---------------- output offsets (f32 elements) ----------------
#define O_FM    0ULL
#define O_TRIP  67108864ULL
#define O_KL    67108865ULL
#define O_DIST  67108866ULL
#define O_AATT  67108867ULL
#define O_NATT  67141635ULL
#define O_ANATT 67174403ULL
#define O_NAATT 67207171ULL

// ---------------- ws offsets (bytes), total ~18.6 MB (ws_size ~1 GB) ----------------
#define WS_ATTB  0ULL          // att bf16 [65536][128] (k<64: vs Amem, k>=64: vs Nmem)
#define WS_BCT   16777216ULL   // bf16 [512 n][128 k]: k<64 = pam^T, k>=64 = pnm^T
#define WS_PVT   16908288ULL   // bf16 [512 n][64 k] = pnv^T
#define WS_PAM   16973824ULL   // f32 [64][512]  (Amem @ W_mu)
#define WS_PNM   17104896ULL   // f32 [64][512]  (Nmem @ W_mu)
#define WS_PNV   17235968ULL   // f32 [64][512]  (Nmem @ W_var)
#define WS_MBH   17367040ULL   // bf16 [128 k][512 d] mem hi  (k<64 Amem, else Nmem)
#define WS_MBL   17498112ULL   // bf16 [128 k][512 d] mem lo  (residual)
#define WS_TATT  17629184ULL   // f32 [3][32768] (0=A_att,1=N_att,2=N_Aatt)
#define WS_IDX   18022400ULL   // int [3][64][40]
#define WS_GATH  18053120ULL   // f32 [3][64][512]
#define WS_NORM  18446336ULL   // f32 [128]
#define WS_KL    18446848ULL   // f32 accumulator
#define WS_TRIPB 18447360ULL   // f32 [64]
#define WS_SUM   18447616ULL   // f32 [64][512] anchor partial sums

__device__ __forceinline__ u16 f2bf(float f) {
    union { float f; unsigned int u; } c; c.f = f;
    unsigned int r = c.u + 0x7fffu + ((c.u >> 16) & 1u);
    return (u16)(r >> 16);
}
__device__ __forceinline__ float bf2f(u16 h) {
    union { unsigned int u; float f; } c; c.u = ((unsigned int)h) << 16;
    return c.f;
}

__device__ __forceinline__ float blk_sum(float v, float* red) {
    #pragma unroll
    for (int o = 32; o; o >>= 1) v += __shfl_xor(v, o);
    int tid = threadIdx.x;
    if ((tid & 63) == 0) red[tid >> 6] = v;
    __syncthreads();
    float r = red[0] + red[1] + red[2] + red[3];
    __syncthreads();
    return r;
}

// 512-thread version: waves 4-7 contribute v=0 -> red[4..7]=0, bit-identical sum
__device__ __forceinline__ float blk_sum8(float v, float* red, int tid) {
    #pragma unroll
    for (int o = 32; o; o >>= 1) v += __shfl_xor(v, o);
    if ((tid & 63) == 0) red[tid >> 6] = v;
    __syncthreads();
    float r = red[0];
    #pragma unroll
    for (int i = 1; i < 8; ++i) r += red[i];
    __syncthreads();
    return r;
}

// stage a 128x32 bf16 tile into LDS linearly -- 512-thread version (one 16B load each)
__device__ __forceinline__ void stage32_512(const u16* __restrict__ g, int row0, int ld, int k0,
                                            u16* s, int tid) {
    const u16* src = g + (size_t)(row0 + (tid >> 2)) * ld + k0 + (tid & 3) * 8;
    __builtin_amdgcn_global_load_lds((const __attribute__((address_space(1))) void*)src,
                                     (__attribute__((address_space(3))) void*)(s + tid * 8),
                                     16, 0, 0);
}

// ---------------- k_pp: prep (256 blocks) + proj (192 blocks) ----------------
__global__ __launch_bounds__(256) void k_pp(const float* __restrict__ Amem, const float* __restrict__ Nmem,
                                            const float* __restrict__ Wmu, const float* __restrict__ Wvar,
                                            char* __restrict__ ws) {
    __shared__ float mr[512];
    int bid = blockIdx.x, tid = threadIdx.x;
    if (bid < 256) {
        int i = bid * 256 + tid;
        if (i == 0) *(float*)(ws + WS_KL) = 0.f;
        if (i < 32768) ((float*)(ws + WS_SUM))[i] = 0.f;
        int k = i >> 9, d = i & 511;
        float v = (k < 64) ? Amem[(size_t)k * 512 + d] : Nmem[(size_t)(k - 64) * 512 + d];
        u16 h = f2bf(v);
        ((u16*)(ws + WS_MBH))[i] = h;
        ((u16*)(ws + WS_MBL))[i] = f2bf(v - bf2f(h));
        return;
    }
    int pb = bid - 256;
    float* pam = (float*)(ws + WS_PAM);
    float* pnm = (float*)(ws + WS_PNM);
    float* pnv = (float*)(ws + WS_PNV);
    u16* bct = (u16*)(ws + WS_BCT);
    u16* pvt = (u16*)(ws + WS_PVT);
    int mat = pb >> 6, k = pb & 63;
    const float* mrow = ((mat == 0) ? Amem : Nmem) + (size_t)k * 512;
    const float* W = (mat == 2) ? Wvar : Wmu;
    mr[tid] = mrow[tid]; mr[tid + 256] = mrow[tid + 256];
    __syncthreads();
    float s0 = 0.f, s1 = 0.f;
    for (int d = 0; d < 512; ++d) {
        float m = mr[d];
        s0 += m * W[(size_t)d * 512 + tid];
        s1 += m * W[(size_t)d * 512 + tid + 256];
    }
    if (mat == 0) {
        pam[(size_t)k * 512 + tid] = s0; pam[(size_t)k * 512 + tid + 256] = s1;
        bct[(size_t)tid * 128 + k] = f2bf(s0); bct[(size_t)(tid + 256) * 128 + k] = f2bf(s1);
    } else if (mat == 1) {
        pnm[(size_t)k * 512 + tid] = s0; pnm[(size_t)k * 512 + tid + 256] = s1;
        bct[(size_t)tid * 128 + 64 + k] = f2bf(s0); bct[(size_t)(tid + 256) * 128 + 64 + k] = f2bf(s1);
    } else {
        pnv[(size_t)k * 512 + tid] = s0; pnv[(size_t)k * 512 + tid + 256] = s1;
        pvt[(size_t)tid * 64 + k] = f2bf(s0); pvt[(size_t)(tid + 256) * 64 + k] = f2bf(s1);
    }
}

// ---------------- dots via split-bf16 MFMA (unchanged from round 12) ----------------
__global__ __launch_bounds__(512) void k_dots(const float* __restrict__ x, char* __restrict__ ws,
                                              float* __restrict__ out) {
    __shared__ u16 sXh[128 * 32];
    __shared__ u16 sXl[128 * 32];
    __shared__ u16 sBh[128 * 32];
    __shared__ u16 sBl[128 * 32];

    int tid = threadIdx.x;
    int row0 = blockIdx.x * 128;
    const u16* mbh = (const u16*)(ws + WS_MBH);
    const u16* mbl = (const u16*)(ws + WS_MBL);
    u16* attb = (u16*)(ws + WS_ATTB);
    int lane = tid & 63, wid = tid >> 6;
    int cl = lane & 15, rq = lane >> 4;

    f32x4 acc[8];
    #pragma unroll
    for (int i = 0; i < 8; ++i) acc[i] = (f32x4)0.f;

    for (int dc = 0; dc < 16; ++dc) {
        int d0 = dc * 32;
        {
            int r = tid >> 2, q4 = tid & 3;
            const float* sp = x + (size_t)(row0 + r) * 512 + d0 + q4 * 8;
            float* op = out + (size_t)(row0 + r) * 1024 + d0 + q4 * 8;
            f32x4 v0 = *(const f32x4*)(sp);
            f32x4 v1 = *(const f32x4*)(sp + 4);
            *(f32x4*)(op) = v0;
            *(f32x4*)(op + 4) = v1;
            s16x8 hs, ls;
            #pragma unroll
            for (int j = 0; j < 4; ++j) {
                u16 h0 = f2bf(v0[j]); hs[j] = (short)h0; ls[j] = (short)f2bf(v0[j] - bf2f(h0));
                u16 h1 = f2bf(v1[j]); hs[4 + j] = (short)h1; ls[4 + j] = (short)f2bf(v1[j] - bf2f(h1));
            }
            *(s16x8*)&sXh[r * 32 + q4 * 8] = hs;
            *(s16x8*)&sXl[r * 32 + q4 * 8] = ls;
        }
        stage32_512(mbh, 0, 512, d0, sBh, tid);
        stage32_512(mbl, 0, 512, d0, sBl, tid);
        __syncthreads();
        s16x8 axh = *(const s16x8*)&sXh[(wid * 16 + cl) * 32 + rq * 8];
        s16x8 axl = *(const s16x8*)&sXl[(wid * 16 + cl) * 32 + rq * 8];
        #pragma unroll
        for (int ni = 0; ni < 8; ++ni) {
            s16x8 bh = *(const s16x8*)&sBh[(ni * 16 + cl) * 32 + rq * 8];
            s16x8 bl = *(const s16x8*)&sBl[(ni * 16 + cl) * 32 + rq * 8];
            acc[ni] = __builtin_amdgcn_mfma_f32_16x16x32_bf16(axh, bh, acc[ni], 0, 0, 0);
            acc[ni] = __builtin_amdgcn_mfma_f32_16x16x32_bf16(axh, bl, acc[ni], 0, 0, 0);
            acc[ni] = __builtin_amdgcn_mfma_f32_16x16x32_bf16(axl, bh, acc[ni], 0, 0, 0);
        }
        __syncthreads();
    }

    #pragma unroll
    for (int ni = 0; ni < 8; ++ni) {
        #pragma unroll
        for (int q = 0; q < 4; ++q) {
            float logit = acc[ni][q] * 0.044194173824159216f;  // 1/sqrt(512)
            float av = 1.f / (1.f + expf(-logit));
            acc[ni][q] = av;
            attb[(size_t)(row0 + wid * 16 + rq * 4 + q) * 128 + ni * 16 + cl] = f2bf(av);
        }
    }

    unsigned long long gmask = 0xFFFFull << (lane & 48);
    float* tatt = (float*)(ws + WS_TATT);
    int half = row0 >> 15;
    #pragma unroll
    for (int q = 0; q < 4; ++q) {
        #pragma unroll
        for (int side = 0; side < 2; ++side) {
            float v0 = acc[side * 4 + 0][q], v1 = acc[side * 4 + 1][q];
            float v2 = acc[side * 4 + 2][q], v3 = acc[side * 4 + 3][q];
            float sum5 = 0.f;
            #pragma unroll
            for (int it = 0; it < 5; ++it) {
                float m = v0; int jm = 0;
                if (v1 > m) { m = v1; jm = 1; }
                if (v2 > m) { m = v2; jm = 2; }
                if (v3 > m) { m = v3; jm = 3; }
                float g = m;
                g = fmaxf(g, __shfl_xor(g, 1));
                g = fmaxf(g, __shfl_xor(g, 2));
                g = fmaxf(g, __shfl_xor(g, 4));
                g = fmaxf(g, __shfl_xor(g, 8));
                sum5 += g;
                unsigned long long bl = __ballot(m == g) & gmask;
                int owner = __ffsll(bl) - 1;
                if (lane == owner) {
                    if (jm == 0) v0 = -INFINITY;
                    else if (jm == 1) v1 = -INFINITY;
                    else if (jm == 2) v2 = -INFINITY;
                    else v3 = -INFINITY;
                }
            }
            if (cl == 0) {
                float tv = sum5 / 5.f;
                int lr = (row0 + wid * 16 + rq * 4 + q) & 32767;
                if (half) {
                    if (side == 0) { out[O_AATT + lr]  = tv; tatt[lr] = tv; }
                    else           { out[O_NAATT + lr] = tv; tatt[2 * 32768 + lr] = tv; }
                } else {
                    if (side == 0) { out[O_ANATT + lr] = tv; }
                    else           { out[O_NATT + lr]  = tv; tatt[32768 + lr] = tv; }
                }
            }
        }
    }
}

// ---------------- k_tg: top-33 rank + immediate gather of x means ----------------
__global__ __launch_bounds__(256) void k_tg(const float* __restrict__ tatt, int* __restrict__ idx,
                                            const float* __restrict__ x, float* __restrict__ gath) {
    __shared__ float vals[512];
    __shared__ int il[40];
    int s = blockIdx.x >> 6, b = blockIdx.x & 63, tid = threadIdx.x;
    const float* src = tatt + (size_t)s * 32768 + b * 512;
    vals[tid] = src[tid]; vals[tid + 256] = src[tid + 256];
    __syncthreads();
    #pragma unroll
    for (int e = 0; e < 2; ++e) {
        int i = tid + e * 256;
        float v = vals[i];
        int rank = 0;
        for (int j = 0; j < 512; j += 4) {
            f32x4 w4 = *(const f32x4*)&vals[j];
            rank += (w4.x > v) || (w4.x == v && (j + 0) < i);
            rank += (w4.y > v) || (w4.y == v && (j + 1) < i);
            rank += (w4.z > v) || (w4.z == v && (j + 2) < i);
            rank += (w4.w > v) || (w4.w == v && (j + 3) < i);
        }
        if (rank < 33) { idx[(s * 64 + b) * 40 + rank] = i; il[rank] = i; }
    }
    __syncthreads();
    int srcb = (s == 1) ? b : 64 + b;
    const float* xb = x + (size_t)srcb * 262144;
    int d0 = tid * 2;
    float a0 = 0.f, a1 = 0.f;
    for (int i = 0; i < 33; ++i) {
        const float* p = xb + (size_t)il[i] * 512 + d0;
        a0 += p[0]; a1 += p[1];
    }
    gath[((size_t)s * 64 + b) * 512 + d0]     = a0 / 33.f;
    gath[((size_t)s * 64 + b) * 512 + d0 + 1] = a1 / 33.f;
}

// ---------------- k_post bodies ----------------
__device__ __forceinline__ void body_G1(char* smem, int m0, int c0, int tid,
                                        const u16* __restrict__ attb, const u16* __restrict__ bct,
                                        const u16* __restrict__ pvt, const float* __restrict__ bmu,
                                        const float* __restrict__ bvar, const float* __restrict__ epsv,
                                        float* __restrict__ fm, float* __restrict__ klacc) {
    u16* sAA = (u16*)(smem);
    u16* sAN = (u16*)(smem + 8192);
    u16* sBA = (u16*)(smem + 16384);
    u16* sBN = (u16*)(smem + 24576);
    u16* sBV = (u16*)(smem + 32768);
    float* red = (float*)(smem + 40960);
    int lane = tid & 63, wid = tid >> 6;
    int wr = wid >> 2, wc = wid & 3;
    int cl = lane & 15, rq = lane >> 4;

    f32x4 aA[4][2], aN[4][2], aV[4][2];
    #pragma unroll
    for (int i = 0; i < 4; ++i)
        #pragma unroll
        for (int j = 0; j < 2; ++j) { aA[i][j] = (f32x4)0.f; aN[i][j] = (f32x4)0.f; aV[i][j] = (f32x4)0.f; }

    for (int kt = 0; kt < 2; ++kt) {
        stage32_512(attb, m0, 128, kt * 32, sAA, tid);
        stage32_512(attb, m0, 128, 64 + kt * 32, sAN, tid);
        stage32_512(bct, c0, 128, kt * 32, sBA, tid);
        stage32_512(bct, c0, 128, 64 + kt * 32, sBN, tid);
        stage32_512(pvt, c0, 64, kt * 32, sBV, tid);
        __syncthreads();
        s16x8 fA[4], fN[4], bA[2], bN[2], bV[2];
        #pragma unroll
        for (int i = 0; i < 4; ++i) {
            fA[i] = *(const s16x8*)&sAA[(wr * 64 + i * 16 + cl) * 32 + rq * 8];
            fN[i] = *(const s16x8*)&sAN[(wr * 64 + i * 16 + cl) * 32 + rq * 8];
        }
        #pragma unroll
        for (int n = 0; n < 2; ++n) {
            bA[n] = *(const s16x8*)&sBA[(wc * 32 + n * 16 + cl) * 32 + rq * 8];
            bN[n] = *(const s16x8*)&sBN[(wc * 32 + n * 16 + cl) * 32 + rq * 8];
            bV[n] = *(const s16x8*)&sBV[(wc * 32 + n * 16 + cl) * 32 + rq * 8];
        }
        #pragma unroll
        for (int mi = 0; mi < 4; ++mi)
            #pragma unroll
            for (int ni = 0; ni < 2; ++ni) {
                aA[mi][ni] = __builtin_amdgcn_mfma_f32_16x16x32_bf16(fA[mi], bA[ni], aA[mi][ni], 0, 0, 0);
                aN[mi][ni] = __builtin_amdgcn_mfma_f32_16x16x32_bf16(fN[mi], bN[ni], aN[mi][ni], 0, 0, 0);
                aV[mi][ni] = __builtin_amdgcn_mfma_f32_16x16x32_bf16(fN[mi], bV[ni], aV[mi][ni], 0, 0, 0);
            }
        __syncthreads();
    }

    float kll = 0.f;
    #pragma unroll
    for (int mi = 0; mi < 4; ++mi)
        #pragma unroll
        for (int ni = 0; ni < 2; ++ni) {
            int col = c0 + wc * 32 + ni * 16 + cl;
            int rowb = m0 + wr * 64 + mi * 16 + rq * 4;
            float bm = bmu[col], bv = bvar[col];
            #pragma unroll
            for (int q = 0; q < 4; ++q) {
                int row = rowb + q;
                float muN = aN[mi][ni][q] + bm;
                float var = aV[mi][ni][q] + bv;
                float ev = expf(var);
                float muA = aA[mi][ni][q] + bm;
                fm[(size_t)row * 1024 + 512 + col] =
                    muN + epsv[(size_t)row * 512 + col] * sqrtf(ev) + muA;
                kll += 1.f + var - muN * muN - ev;
            }
        }
    #pragma unroll
    for (int o = 32; o; o >>= 1) kll += __shfl_xor(kll, o);
    if (lane == 0) red[wid] = kll;
    __syncthreads();
    if (tid == 0) {
        float s = 0.f;
        #pragma unroll
        for (int i = 0; i < 8; ++i) s += red[i];
        atomicAdd(klacc, s);
    }
}

__device__ __forceinline__ void body_G3(char* smem, int m0, int c0, int tid,
                                        const u16* __restrict__ attb, const u16* __restrict__ bct,
                                        const float* __restrict__ bmu, float* __restrict__ fm) {
    u16* sA = (u16*)(smem);
    u16* sB = (u16*)(smem + 8192);
    int lane = tid & 63, wid = tid >> 6;
    int wr = wid >> 2, wc = wid & 3;
    int cl = lane & 15, rq = lane >> 4;

    f32x4 acc[4][2];
    #pragma unroll
    for (int i = 0; i < 4; ++i)
        #pragma unroll
        for (int j = 0; j < 2; ++j) acc[i][j] = (f32x4)0.f;

    for (int kt = 0; kt < 4; ++kt) {
        stage32_512(attb, 32768 + m0, 128, kt * 32, sA, tid);
        stage32_512(bct, c0, 128, kt * 32, sB, tid);
        __syncthreads();
        s16x8 fa[4], fb[2];
        #pragma unroll
        for (int i = 0; i < 4; ++i)
            fa[i] = *(const s16x8*)&sA[(wr * 64 + i * 16 + cl) * 32 + rq * 8];
        #pragma unroll
        for (int n = 0; n < 2; ++n)
            fb[n] = *(const s16x8*)&sB[(wc * 32 + n * 16 + cl) * 32 + rq * 8];
        #pragma unroll
        for (int mi = 0; mi < 4; ++mi)
            #pragma unroll
            for (int ni = 0; ni < 2; ++ni)
                acc[mi][ni] = __builtin_amdgcn_mfma_f32_16x16x32_bf16(fa[mi], fb[ni], acc[mi][ni], 0, 0, 0);
        __syncthreads();
    }
    #pragma unroll
    for (int mi = 0; mi < 4; ++mi)
        #pragma unroll
        for (int ni = 0; ni < 2; ++ni) {
            int col = c0 + wc * 32 + ni * 16 + cl;
            int rowb = 32768 + m0 + wr * 64 + mi * 16 + rq * 4;
            float bm2 = 2.f * bmu[col];
            #pragma unroll
            for (int q = 0; q < 4; ++q)
                fm[(size_t)(rowb + q) * 1024 + 512 + col] = acc[mi][ni][q] + bm2;
        }
}

__device__ __forceinline__ void body_g2a(char* smem, int blk, int tid,
                                         const int* __restrict__ idx, const u16* __restrict__ attb,
                                         const float* __restrict__ pnm, const float* __restrict__ pnv,
                                         const float* __restrict__ bmu, const float* __restrict__ bvar,
                                         const float* __restrict__ epsv, float* __restrict__ SUM) {
    float* arow = (float*)smem;
    int b = blk / 3, seg = blk % 3;
    float s0 = 0.f, s1 = 0.f;
    for (int i = seg * 11; i < seg * 11 + 11; ++i) {
        int t = idx[(64 + b) * 40 + i];   // N_idx
        size_t r = (size_t)b * 512 + t;
        __syncthreads();
        if (tid < 64) arow[tid] = bf2f(attb[r * 128 + 64 + tid]);
        __syncthreads();
        if (tid < 256) {
            float mu0 = bmu[tid], mu1 = bmu[tid + 256];
            float v0 = bvar[tid], v1 = bvar[tid + 256];
            for (int k = 0; k < 64; ++k) {
                float a = arow[k];
                mu0 += a * pnm[(size_t)k * 512 + tid];
                mu1 += a * pnm[(size_t)k * 512 + tid + 256];
                v0  += a * pnv[(size_t)k * 512 + tid];
                v1  += a * pnv[(size_t)k * 512 + tid + 256];
            }
            s0 += mu0 + bf2f(f2bf(0.f)) + epsv[r * 512 + tid]       * sqrtf(expf(v0));
            s1 += mu1 + epsv[r * 512 + tid + 256] * sqrtf(expf(v1));
        }
    }
    if (tid < 256) {
        atomicAdd(&SUM[(size_t)b * 512 + tid], s0);
        atomicAdd(&SUM[(size_t)b * 512 + tid + 256], s1);
    }
}

__device__ __forceinline__ void body_g2b(char* smem, int b, int tid,
                                         const int* __restrict__ idx, const u16* __restrict__ attb,
                                         const float* __restrict__ pam, const float* __restrict__ bmu,
                                         float* __restrict__ norms) {
    float* meanA = (float*)smem;
    float* red = (float*)(smem + 256);
    if (tid < 64) {
        float s = 0.f;
        for (int i = 0; i < 33; ++i) {
            int t = idx[b * 40 + i];      // A_idx
            s += bf2f(attb[(size_t)(32768 + b * 512 + t) * 128 + tid]);
        }
        meanA[tid] = s * (1.f / 33.f);
    }
    __syncthreads();
    float ssv = 0.f;
    if (tid < 256) {
        float s0 = bmu[tid], s1 = bmu[tid + 256];
        #pragma unroll 4
        for (int k = 0; k < 64; ++k) {
            float m = meanA[k];
            s0 += m * pam[(size_t)k * 512 + tid];
            s1 += m * pam[(size_t)k * 512 + tid + 256];
        }
        ssv = s0 * s0 + s1 * s1;
    }
    float ss = blk_sum8(ssv, red, tid);
    if (tid == 0) norms[64 + b] = sqrtf(ss);
}

// ---------------- k_post: kG1 (1024) + kG3 (1024) + g2a (192) + g2b (64) ----------------
__global__ __launch_bounds__(512) void k_post(const u16* __restrict__ attb, const u16* __restrict__ bct,
                                              const u16* __restrict__ pvt, const float* __restrict__ bmu,
                                              const float* __restrict__ bvar, const float* __restrict__ epsv,
                                              const int* __restrict__ idx, const float* __restrict__ pam,
                                              const float* __restrict__ pnm, const float* __restrict__ pnv,
                                              float* __restrict__ fm, float* __restrict__ klacc,
                                              float* __restrict__ SUM, float* __restrict__ norms) {
    __shared__ __align__(16) char smem[41024];
    int bid = blockIdx.x, tid = threadIdx.x;
    if (bid < 1024) {
        body_G1(smem, (bid >> 2) * 128, (bid & 3) * 128, tid, attb, bct, pvt, bmu, bvar, epsv, fm, klacc);
    } else if (bid < 2048) {
        int b2 = bid - 1024;
        body_G3(smem, (b2 >> 2) * 128, (b2 & 3) * 128, tid, attb, bct, bmu, fm);
    } else if (bid < 2240) {
        body_g2a(smem, bid - 2048, tid, idx, attb, pnm, pnv, bmu, bvar, epsv, SUM);
    } else {
        body_g2b(smem, bid - 2240, tid, idx, attb, pam, bmu, norms);
    }
}

// ---------------- k_nt: norm2a (64) + triplet (64) ----------------
__global__ __launch_bounds__(256) void k_nt(const float* __restrict__ SUM, const float* __restrict__ gath,
                                            float* __restrict__ norms, float* __restrict__ tripb) {
    __shared__ float red[8];
    int bid = blockIdx.x, tid = threadIdx.x;
    if (bid < 64) {
        int b = bid;
        float s0 = SUM[(size_t)b * 512 + tid] / 33.f;
        float s1 = SUM[(size_t)b * 512 + tid + 256] / 33.f;
        float ss = blk_sum(s0 * s0 + s1 * s1, red);
        if (tid == 0) norms[b] = sqrtf(ss);
    } else {
        int b = bid - 64;
        const float* a = gath + (size_t)(64 + b) * 512;
        const float* p = gath + (size_t)(128 + b) * 512;
        const float* n = gath + (size_t)(b) * 512;
        float a0 = a[tid], a1 = a[tid + 256];
        float p0 = p[tid], p1 = p[tid + 256];
        float n0 = n[tid], n1 = n[tid + 256];
        float na  = sqrtf(blk_sum(a0 * a0 + a1 * a1, red));
        float npv = sqrtf(blk_sum(p0 * p0 + p1 * p1, red));
        float nn  = sqrtf(blk_sum(n0 * n0 + n1 * n1, red));
        float e0 = a0 / na - p0 / npv + 1e-6f, e1 = a1 / na - p1 / npv + 1e-6f;
        float f0 = a0 / na - n0 / nn  + 1e-6f, f1 = a1 / na - n1 / nn  + 1e-6f;
        float dap = sqrtf(blk_sum(e0 * e0 + e1 * e1, red));
        float dan = sqrtf(blk_sum(f0 * f0 + f1 * f1, red));
        if (tid == 0) tripb[b] = fmaxf(dap - dan + 1.f, 0.f);
    }
}

// ---------------- finalize: triplet + distance + kl ----------------
__global__ __launch_bounds__(64) void k_final(const float* __restrict__ norms, const float* __restrict__ klacc,
                                              const float* __restrict__ tripb, float* __restrict__ out) {
    int tid = threadIdx.x;
    float v = fmaxf(100.f - norms[64 + tid] + norms[tid], 0.f);
    float t = tripb[tid];
    #pragma unroll
    for (int o = 32; o; o >>= 1) { v += __shfl_xor(v, o); t += __shfl_xor(t, o); }
    if (tid == 0) {
        out[O_DIST] = v / 64.f;
        out[O_TRIP] = t / 64.f;
        out[O_KL]   = -0.5f * (*klacc) / 32768.f;
    }
}

extern "C" void kernel_launch(void* const* d_in, const int* in_sizes, int n_in,
                              void* d_out, int out_size, void* d_ws, size_t ws_size,
                              hipStream_t stream) {
    const float* x    = (const float*)d_in[0];
    const float* Amem = (const float*)d_in[1];
    const float* Nmem = (const float*)d_in[2];
    const float* Wmu  = (const float*)d_in[3];
    const float* bmu  = (const float*)d_in[4];
    const float* Wvar = (const float*)d_in[5];
    const float* bvar = (const float*)d_in[6];
    const float* eps  = (const float*)d_in[7];
    float* out = (float*)d_out;
    char* ws = (char*)d_ws;
    const u16* attb  = (const u16*)(ws + WS_ATTB);
    const u16* bct   = (const u16*)(ws + WS_BCT);
    const u16* pvt   = (const u16*)(ws + WS_PVT);
    const float* pam = (const float*)(ws + WS_PAM);
    const float* pnm = (const float*)(ws + WS_PNM);
    const float* pnv = (const float*)(ws + WS_PNV);
    const int* idx   = (const int*)(ws + WS_IDX);

    k_pp<<<448, 256, 0, stream>>>(Amem, Nmem, Wmu, Wvar, ws);
    k_dots<<<512, 512, 0, stream>>>(x, ws, out);
    k_tg<<<192, 256, 0, stream>>>((const float*)(ws + WS_TATT), (int*)(ws + WS_IDX), x,
                                  (float*)(ws + WS_GATH));
    k_post<<<2304, 512, 0, stream>>>(attb, bct, pvt, bmu, bvar, eps, idx, pam, pnm, pnv,
                                     out, (float*)(ws + WS_KL), (float*)(ws + WS_SUM),
                                     (float*)(ws + WS_NORM));
    k_nt<<<128, 256, 0, stream>>>((const float*)(ws + WS_SUM), (const float*)(ws + WS_GATH),
                                  (float*)(ws + WS_NORM), (float*)(ws + WS_TRIPB));
    k_final<<<1, 64, 0, stream>>>((const float*)(ws + WS_NORM), (const float*)(ws + WS_KL),
                                  (const float*)(ws + WS_TRIPB), out);
}